// Round 1
// baseline (10861.393 us; speedup 1.0000x reference)
//
#include <hip/hip_runtime.h>
#include <hip/hip_bf16.h>

#define S 2048
#define D 768
#define H 12
#define HD 64
#define V 32000
#define R 32
#define DFF 3072
#define NLAYERS 4
#define EPS 1e-6f

// ---------------- embedding gather ----------------
__global__ void k_embed(const int* __restrict__ ids, const float* __restrict__ emb,
                        float* __restrict__ x) {
    int s = blockIdx.x;
    int row = ids[s];
    for (int d = threadIdx.x; d < D; d += blockDim.x)
        x[s * D + d] = emb[row * D + d];
}

// ---------------- layernorm (one row per block, 256 thr) ----------------
__global__ __launch_bounds__(256) void k_ln(const float* __restrict__ x,
                                            const float* __restrict__ g,
                                            const float* __restrict__ b,
                                            float* __restrict__ out) {
    int s = blockIdx.x;
    int t = threadIdx.x;
    const float* xr = x + s * D;
    float e0 = xr[t], e1 = xr[t + 256], e2 = xr[t + 512];
    float sum = e0 + e1 + e2;
    float sq = e0 * e0 + e1 * e1 + e2 * e2;
    #pragma unroll
    for (int m = 1; m < 64; m <<= 1) {
        sum += __shfl_xor(sum, m);
        sq  += __shfl_xor(sq, m);
    }
    __shared__ float ssum[4], ssq[4];
    int w = t >> 6;
    if ((t & 63) == 0) { ssum[w] = sum; ssq[w] = sq; }
    __syncthreads();
    sum = ssum[0] + ssum[1] + ssum[2] + ssum[3];
    sq  = ssq[0] + ssq[1] + ssq[2] + ssq[3];
    float mean = sum * (1.0f / D);
    float var  = sq * (1.0f / D) - mean * mean;
    float rs = rsqrtf(var + EPS);
    float* orow = out + s * D;
    orow[t]       = (e0 - mean) * rs * g[t]       + b[t];
    orow[t + 256] = (e1 - mean) * rs * g[t + 256] + b[t + 256];
    orow[t + 512] = (e2 - mean) * rs * g[t + 512] + b[t + 512];
}

// ---------------- fp32 GEMM: C[M,N] = X[M,K] @ W[N,K]^T ----------------
// 64x64 tile, BK=16, 256 threads, 4x4 per thread. K % 16 == 0, N % 64 == 0.
#define BM 64
#define BN 64
#define BK 16
__global__ __launch_bounds__(256) void k_gemm(const float* __restrict__ X, int lda,
                                              const float* __restrict__ W,
                                              float* __restrict__ C, int N, int K) {
    __shared__ float As[BK][BM + 4];
    __shared__ float Bs[BK][BN + 4];
    int tid = threadIdx.x;
    int m0 = blockIdx.y * BM, n0 = blockIdx.x * BN;
    int lrow = tid >> 2;
    int lk4 = (tid & 3) * 4;
    int tx = tid & 15, ty = tid >> 4;
    float acc[4][4] = {};
    for (int k0 = 0; k0 < K; k0 += BK) {
        float4 a = *(const float4*)(X + (long)(m0 + lrow) * lda + k0 + lk4);
        float4 bb = *(const float4*)(W + (long)(n0 + lrow) * K + k0 + lk4);
        As[lk4 + 0][lrow] = a.x; As[lk4 + 1][lrow] = a.y;
        As[lk4 + 2][lrow] = a.z; As[lk4 + 3][lrow] = a.w;
        Bs[lk4 + 0][lrow] = bb.x; Bs[lk4 + 1][lrow] = bb.y;
        Bs[lk4 + 2][lrow] = bb.z; Bs[lk4 + 3][lrow] = bb.w;
        __syncthreads();
        #pragma unroll
        for (int kk = 0; kk < BK; kk++) {
            float av[4], bv[4];
            #pragma unroll
            for (int i = 0; i < 4; i++) av[i] = As[kk][ty * 4 + i];
            #pragma unroll
            for (int j = 0; j < 4; j++) bv[j] = Bs[kk][tx * 4 + j];
            #pragma unroll
            for (int i = 0; i < 4; i++)
                #pragma unroll
                for (int j = 0; j < 4; j++)
                    acc[i][j] += av[i] * bv[j];
        }
        __syncthreads();
    }
    #pragma unroll
    for (int i = 0; i < 4; i++) {
        float4 o = make_float4(acc[i][0], acc[i][1], acc[i][2], acc[i][3]);
        *(float4*)(C + (long)(m0 + ty * 4 + i) * N + n0 + tx * 4) = o;
    }
}

// ---------------- LoRA: T[M,R] = X[M,K] @ A[K,R] ----------------
// block 256 = 8 m-rows x 32 r. grid = S/8.
__global__ __launch_bounds__(256) void k_lora_t(const float* __restrict__ X, int lda, int K,
                                                const float* __restrict__ A,
                                                float* __restrict__ T) {
    int m = blockIdx.x * 8 + (threadIdx.x >> 5);
    int r = threadIdx.x & 31;
    const float* xr = X + (long)m * lda;
    float s0 = 0.f, s1 = 0.f, s2 = 0.f, s3 = 0.f;
    for (int k = 0; k < K; k += 4) {
        s0 += xr[k + 0] * A[(k + 0) * R + r];
        s1 += xr[k + 1] * A[(k + 1) * R + r];
        s2 += xr[k + 2] * A[(k + 2) * R + r];
        s3 += xr[k + 3] * A[(k + 3) * R + r];
    }
    T[m * R + r] = (s0 + s1) + (s2 + s3);
}

// ---------------- LoRA add: C[M,N] += (1/R) * T[M,R] @ B[R,N] ----------------
__global__ __launch_bounds__(256) void k_lora_add(const float* __restrict__ T,
                                                  const float* __restrict__ B,
                                                  float* __restrict__ C, int N) {
    int n = blockIdx.x * 256 + threadIdx.x;
    int m = blockIdx.y;
    const float* tr = T + m * R;
    float sum = 0.f;
    #pragma unroll
    for (int r = 0; r < R; r++) sum += tr[r] * B[r * N + n];
    C[(long)m * N + n] += sum * (1.0f / R);
}

// ---------------- attention: ALiBi + causal, one wave per (row, head) -------
// qkv layout: [S, 3, H, HD] flattened row stride 3*D. blocks (S/4, H), 4 waves.
__global__ __launch_bounds__(256) void k_attn(const float* __restrict__ qkv,
                                              const float* __restrict__ slopes,
                                              float* __restrict__ ao) {
    __shared__ float srow[4][S];
    __shared__ float qs[4][HD];
    int w = threadIdx.x >> 6, lane = threadIdx.x & 63;
    int i = blockIdx.x * 4 + w;
    int h = blockIdx.y;
    const float* kbase = qkv + D + h * HD;
    const float* vbase = qkv + 2 * D + h * HD;
    float slope = slopes[h];
    qs[w][lane] = qkv[(long)i * (3 * D) + h * HD + lane] * 0.125f; // 1/sqrt(64)
    __syncthreads();
    // pass 1: scores for own j's, track lane max
    float mloc = -3.0e38f;
    for (int j = lane; j <= i; j += 64) {
        const float* kr = kbase + (long)j * (3 * D);
        float s = 0.f;
        #pragma unroll
        for (int d = 0; d < HD; d++) s += qs[w][d] * kr[d];
        s += slope * (float)(j - i);
        srow[w][j] = s;
        mloc = fmaxf(mloc, s);
    }
    #pragma unroll
    for (int m = 1; m < 64; m <<= 1) mloc = fmaxf(mloc, __shfl_xor(mloc, m));
    // exp + lane sum
    float lsum = 0.f;
    for (int j = lane; j <= i; j += 64) {
        float e = __expf(srow[w][j] - mloc);
        srow[w][j] = e;
        lsum += e;
    }
    #pragma unroll
    for (int m = 1; m < 64; m <<= 1) lsum += __shfl_xor(lsum, m);
    __syncthreads();  // make srow visible across lanes
    // pass 2: o[lane] = sum_j p_j * V[j][lane]
    float o0 = 0.f, o1 = 0.f, o2 = 0.f, o3 = 0.f;
    int j = 0;
    for (; j + 3 <= i; j += 4) {
        o0 += srow[w][j + 0] * vbase[(long)(j + 0) * (3 * D) + lane];
        o1 += srow[w][j + 1] * vbase[(long)(j + 1) * (3 * D) + lane];
        o2 += srow[w][j + 2] * vbase[(long)(j + 2) * (3 * D) + lane];
        o3 += srow[w][j + 3] * vbase[(long)(j + 3) * (3 * D) + lane];
    }
    for (; j <= i; j++)
        o0 += srow[w][j] * vbase[(long)j * (3 * D) + lane];
    float o = (o0 + o1) + (o2 + o3);
    ao[(long)i * D + h * HD + lane] = o / lsum;
}

// ---------------- residual with LayerScale: x += ls * y ----------------
__global__ void k_resid(float* __restrict__ x, const float* __restrict__ y,
                        const float* __restrict__ ls) {
    int idx = blockIdx.x * 256 + threadIdx.x;
    x[idx] += ls[idx % D] * y[idx];
}

// ---------------- SwiGLU in place: hidden[:, :DFF] = silu(g) * a ------------
__global__ void k_swiglu(float* __restrict__ hidden) {
    int idx = blockIdx.x * 256 + threadIdx.x; // over S*DFF
    int s = idx / DFF, f = idx % DFF;
    float* row = hidden + (long)s * (2 * DFF);
    float gv = row[f], av = row[DFF + f];
    float sig = 1.0f / (1.0f + __expf(-gv));
    row[f] = gv * sig * av;
}

extern "C" void kernel_launch(void* const* d_in, const int* in_sizes, int n_in,
                              void* d_out, int out_size, void* d_ws, size_t ws_size,
                              hipStream_t stream) {
    const int*   ids    = (const int*)d_in[0];
    const float* emb    = (const float*)d_in[1];
    const float* slopes = (const float*)d_in[2];
    const float* ln1_g  = (const float*)d_in[3];
    const float* ln1_b  = (const float*)d_in[4];
    const float* qkv_W  = (const float*)d_in[5];
    const float* qkv_A  = (const float*)d_in[6];
    const float* qkv_B  = (const float*)d_in[7];
    const float* out_W  = (const float*)d_in[8];
    const float* out_A  = (const float*)d_in[9];
    const float* out_B  = (const float*)d_in[10];
    const float* ln2_g  = (const float*)d_in[11];
    const float* ln2_b  = (const float*)d_in[12];
    const float* fc1_W  = (const float*)d_in[13];
    const float* fc1_A  = (const float*)d_in[14];
    const float* fc1_B  = (const float*)d_in[15];
    const float* fc2_W  = (const float*)d_in[16];
    const float* fc2_A  = (const float*)d_in[17];
    const float* fc2_B  = (const float*)d_in[18];
    const float* ls1    = (const float*)d_in[19];
    const float* ls2    = (const float*)d_in[20];
    const float* lnf_g  = (const float*)d_in[21];
    const float* lnf_b  = (const float*)d_in[22];

    float* ws = (float*)d_ws;
    float* x      = ws;                 // S*D
    float* h      = x + S * D;          // S*D
    float* qkv    = h + S * D;          // S*3D
    float* ao     = qkv + S * 3 * D;    // S*D
    float* proj   = ao + S * D;         // S*D
    float* t      = proj + S * D;       // S*R
    float* hidden = t + S * R;          // S*2*DFF

    k_embed<<<S, 256, 0, stream>>>(ids, emb, x);

    for (int l = 0; l < NLAYERS; l++) {
        // ---- attention block ----
        k_ln<<<S, 256, 0, stream>>>(x, ln1_g + l * D, ln1_b + l * D, h);
        k_gemm<<<dim3(3 * D / BN, S / BM), 256, 0, stream>>>(h, D, qkv_W + (long)l * 3 * D * D, qkv, 3 * D, D);
        k_lora_t<<<S / 8, 256, 0, stream>>>(h, D, D, qkv_A + (long)l * D * R, t);
        k_lora_add<<<dim3(3 * D / 256, S), 256, 0, stream>>>(t, qkv_B + (long)l * R * 3 * D, qkv, 3 * D);
        k_attn<<<dim3(S / 4, H), 256, 0, stream>>>(qkv, slopes, ao);
        k_gemm<<<dim3(D / BN, S / BM), 256, 0, stream>>>(ao, D, out_W + (long)l * D * D, proj, D, D);
        k_lora_t<<<S / 8, 256, 0, stream>>>(ao, D, D, out_A + (long)l * D * R, t);
        k_lora_add<<<dim3(D / 256, S), 256, 0, stream>>>(t, out_B + (long)l * R * D, proj, D);
        k_resid<<<S * D / 256, 256, 0, stream>>>(x, proj, ls1 + l * D);

        // ---- FFN block ----
        k_ln<<<S, 256, 0, stream>>>(x, ln2_g + l * D, ln2_b + l * D, h);
        k_gemm<<<dim3(2 * DFF / BN, S / BM), 256, 0, stream>>>(h, D, fc1_W + (long)l * 2 * DFF * D, hidden, 2 * DFF, D);
        k_lora_t<<<S / 8, 256, 0, stream>>>(h, D, D, fc1_A + (long)l * D * R, t);
        k_lora_add<<<dim3(2 * DFF / 256, S), 256, 0, stream>>>(t, fc1_B + (long)l * R * 2 * DFF, hidden, 2 * DFF);
        k_swiglu<<<S * DFF / 256, 256, 0, stream>>>(hidden);
        k_gemm<<<dim3(D / BN, S / BM), 256, 0, stream>>>(hidden, 2 * DFF, fc2_W + (long)l * D * DFF, proj, D, DFF);
        k_lora_t<<<S / 8, 256, 0, stream>>>(hidden, 2 * DFF, DFF, fc2_A + (long)l * DFF * R, t);
        k_lora_add<<<dim3(D / 256, S), 256, 0, stream>>>(t, fc2_B + (long)l * R * D, proj, D);
        k_resid<<<S * D / 256, 256, 0, stream>>>(x, proj, ls2 + l * D);
    }

    // ---- final LN + tied lm_head ----
    k_ln<<<S, 256, 0, stream>>>(x, lnf_g, lnf_b, h);
    k_gemm<<<dim3(V / BN, S / BM), 256, 0, stream>>>(h, D, emb, (float*)d_out, V, D);
}

// Round 2
// 7534.074 us; speedup vs baseline: 1.4416x; 1.4416x over previous
//
#include <hip/hip_runtime.h>
#include <hip/hip_bf16.h>
#include <stdint.h>

#define S 2048
#define D 768
#define H 12
#define HD 64
#define V 32000
#define R 32
#define DFF 3072
#define NLAYERS 4
#define EPS 1e-6f

typedef __bf16 bf16;
typedef __bf16 bf16x4 __attribute__((ext_vector_type(4)));
typedef __bf16 bf16x8 __attribute__((ext_vector_type(8)));
typedef float f32x4 __attribute__((ext_vector_type(4)));

// ---------------- fp32 -> bf16 conversion (4 elems/thread) ----------------
__global__ __launch_bounds__(256) void k_cvt(const float* __restrict__ in,
                                             bf16* __restrict__ out, long n) {
    long i = ((long)blockIdx.x * 256 + threadIdx.x) * 4;
    if (i >= n) return;
    float4 v = *(const float4*)(in + i);
    bf16x4 o;
    o.x = (bf16)v.x; o.y = (bf16)v.y; o.z = (bf16)v.z; o.w = (bf16)v.w;
    *(bf16x4*)(out + i) = o;
}

// ---------------- embedding gather ----------------
__global__ void k_embed(const int* __restrict__ ids, const float* __restrict__ emb,
                        float* __restrict__ x) {
    int s = blockIdx.x;
    int row = ids[s];
    for (int d = threadIdx.x; d < D; d += blockDim.x)
        x[s * D + d] = emb[row * D + d];
}

// ---------------- layernorm -> bf16 out (one row per block, 256 thr) -------
__global__ __launch_bounds__(256) void k_ln_bf(const float* __restrict__ x,
                                               const float* __restrict__ g,
                                               const float* __restrict__ b,
                                               bf16* __restrict__ out) {
    int s = blockIdx.x;
    int t = threadIdx.x;
    const float* xr = x + s * D;
    float e0 = xr[t], e1 = xr[t + 256], e2 = xr[t + 512];
    float sum = e0 + e1 + e2;
    float sq = e0 * e0 + e1 * e1 + e2 * e2;
    #pragma unroll
    for (int m = 1; m < 64; m <<= 1) {
        sum += __shfl_xor(sum, m);
        sq  += __shfl_xor(sq, m);
    }
    __shared__ float ssum[4], ssq[4];
    int w = t >> 6;
    if ((t & 63) == 0) { ssum[w] = sum; ssq[w] = sq; }
    __syncthreads();
    sum = ssum[0] + ssum[1] + ssum[2] + ssum[3];
    sq  = ssq[0] + ssq[1] + ssq[2] + ssq[3];
    float mean = sum * (1.0f / D);
    float var  = sq * (1.0f / D) - mean * mean;
    float rs = rsqrtf(var + EPS);
    bf16* orow = out + (long)s * D;
    orow[t]       = (bf16)((e0 - mean) * rs * g[t]       + b[t]);
    orow[t + 256] = (bf16)((e1 - mean) * rs * g[t + 256] + b[t + 256]);
    orow[t + 512] = (bf16)((e2 - mean) * rs * g[t + 512] + b[t + 512]);
}

// ---------------- bf16 MFMA GEMM: C[M,N] = X[M,K] @ W[N,K]^T (fp32 out) ----
// 128x128 tile, BK=32, 256 thr = 4 waves (2x2 of 64x64), 4x4 frags of 16x16x32.
// Requires M%128==0, N%128==0, K%32==0, rows 16B-aligned.
__device__ __forceinline__ void gload16(const bf16* g, bf16* l) {
    __builtin_amdgcn_global_load_lds(
        (const __attribute__((address_space(1))) void*)g,
        (__attribute__((address_space(3))) void*)l, 16, 0, 0);
}

__global__ __launch_bounds__(256) void k_gemm_bf(const bf16* __restrict__ X,
                                                 const bf16* __restrict__ W,
                                                 float* __restrict__ C,
                                                 int N, int K) {
    __shared__ bf16 At[128 * 32];
    __shared__ bf16 Bt[128 * 32];
    int tid = threadIdx.x;
    int w = tid >> 6, lane = tid & 63;
    long m0 = (long)blockIdx.y * 128, n0 = (long)blockIdx.x * 128;
    int wr = (w >> 1) * 64, wc = (w & 1) * 64;
    // staging: 8 chunks of 1KB each per tile; wave w does chunks w and w+4
    int c0 = w, c1 = w + 4;
    int rA0 = c0 * 16 + (lane >> 2);   // row within tile for chunk c0
    int rA1 = c1 * 16 + (lane >> 2);
    int ck = (lane & 3) * 8;           // k-element offset (16B)
    int fr = lane & 15;                // fragment row/col within 16
    int fo = (lane >> 4) * 8;          // fragment k-offset
    f32x4 acc[4][4] = {};
    for (int k0 = 0; k0 < K; k0 += 32) {
        gload16(X + (m0 + rA0) * K + k0 + ck, At + c0 * 512);
        gload16(X + (m0 + rA1) * K + k0 + ck, At + c1 * 512);
        gload16(W + (n0 + rA0) * K + k0 + ck, Bt + c0 * 512);
        gload16(W + (n0 + rA1) * K + k0 + ck, Bt + c1 * 512);
        __syncthreads();
        bf16x8 a[4], b[4];
        #pragma unroll
        for (int m = 0; m < 4; m++)
            a[m] = *(const bf16x8*)(At + (wr + m * 16 + fr) * 32 + fo);
        #pragma unroll
        for (int n = 0; n < 4; n++)
            b[n] = *(const bf16x8*)(Bt + (wc + n * 16 + fr) * 32 + fo);
        #pragma unroll
        for (int m = 0; m < 4; m++)
            #pragma unroll
            for (int n = 0; n < 4; n++)
                acc[m][n] = __builtin_amdgcn_mfma_f32_16x16x32_bf16(a[m], b[n], acc[m][n], 0, 0, 0);
        __syncthreads();
    }
    int cr = (lane >> 4) * 4, cc = lane & 15;
    #pragma unroll
    for (int m = 0; m < 4; m++)
        #pragma unroll
        for (int n = 0; n < 4; n++)
            #pragma unroll
            for (int r = 0; r < 4; r++)
                C[(m0 + wr + m * 16 + cr + r) * N + n0 + wc + n * 16 + cc] = acc[m][n][r];
}

// ---------------- LoRA: T[M,R] = Xbf[M,K] @ A[K,R] ----------------
__global__ __launch_bounds__(256) void k_lora_t(const bf16* __restrict__ X, int K,
                                                const float* __restrict__ A,
                                                float* __restrict__ T) {
    int m = blockIdx.x * 8 + (threadIdx.x >> 5);
    int r = threadIdx.x & 31;
    const bf16* xr = X + (long)m * K;
    float s0 = 0.f, s1 = 0.f, s2 = 0.f, s3 = 0.f;
    for (int k = 0; k < K; k += 4) {
        s0 += (float)xr[k + 0] * A[(k + 0) * R + r];
        s1 += (float)xr[k + 1] * A[(k + 1) * R + r];
        s2 += (float)xr[k + 2] * A[(k + 2) * R + r];
        s3 += (float)xr[k + 3] * A[(k + 3) * R + r];
    }
    T[m * R + r] = (s0 + s1) + (s2 + s3);
}

// ---------------- LoRA add: C[M,N] += (1/R) * T[M,R] @ B[R,N] ----------------
__global__ __launch_bounds__(256) void k_lora_add(const float* __restrict__ T,
                                                  const float* __restrict__ B,
                                                  float* __restrict__ C, int N) {
    int n = blockIdx.x * 256 + threadIdx.x;
    int m = blockIdx.y;
    const float* tr = T + m * R;
    float sum = 0.f;
    #pragma unroll
    for (int r = 0; r < R; r++) sum += tr[r] * B[r * N + n];
    C[(long)m * N + n] += sum * (1.0f / R);
}

// ---------------- attention: ALiBi + causal, one wave per (row, head) -------
__global__ __launch_bounds__(256) void k_attn(const float* __restrict__ qkv,
                                              const float* __restrict__ slopes,
                                              bf16* __restrict__ ao) {
    __shared__ float srow[4][S];
    __shared__ float qs[4][HD];
    int w = threadIdx.x >> 6, lane = threadIdx.x & 63;
    int i = blockIdx.x * 4 + w;
    int h = blockIdx.y;
    const float* kbase = qkv + D + h * HD;
    const float* vbase = qkv + 2 * D + h * HD;
    float slope = slopes[h];
    qs[w][lane] = qkv[(long)i * (3 * D) + h * HD + lane] * 0.125f; // 1/sqrt(64)
    __syncthreads();
    float mloc = -3.0e38f;
    for (int j = lane; j <= i; j += 64) {
        const float* kr = kbase + (long)j * (3 * D);
        float s = 0.f;
        #pragma unroll
        for (int d = 0; d < HD; d++) s += qs[w][d] * kr[d];
        s += slope * (float)(j - i);
        srow[w][j] = s;
        mloc = fmaxf(mloc, s);
    }
    #pragma unroll
    for (int m = 1; m < 64; m <<= 1) mloc = fmaxf(mloc, __shfl_xor(mloc, m));
    float lsum = 0.f;
    for (int j = lane; j <= i; j += 64) {
        float e = __expf(srow[w][j] - mloc);
        srow[w][j] = e;
        lsum += e;
    }
    #pragma unroll
    for (int m = 1; m < 64; m <<= 1) lsum += __shfl_xor(lsum, m);
    __syncthreads();
    float o0 = 0.f, o1 = 0.f, o2 = 0.f, o3 = 0.f;
    int j = 0;
    for (; j + 3 <= i; j += 4) {
        o0 += srow[w][j + 0] * vbase[(long)(j + 0) * (3 * D) + lane];
        o1 += srow[w][j + 1] * vbase[(long)(j + 1) * (3 * D) + lane];
        o2 += srow[w][j + 2] * vbase[(long)(j + 2) * (3 * D) + lane];
        o3 += srow[w][j + 3] * vbase[(long)(j + 3) * (3 * D) + lane];
    }
    for (; j <= i; j++)
        o0 += srow[w][j] * vbase[(long)j * (3 * D) + lane];
    float o = (o0 + o1) + (o2 + o3);
    ao[(long)i * D + h * HD + lane] = (bf16)(o / lsum);
}

// ---------------- residual with LayerScale: x += ls * y ----------------
__global__ void k_resid(float* __restrict__ x, const float* __restrict__ y,
                        const float* __restrict__ ls) {
    int idx = blockIdx.x * 256 + threadIdx.x;
    x[idx] += ls[idx % D] * y[idx];
}

// ---------------- SwiGLU: hb[s,f] = silu(g) * a  (bf16 out) ----------------
__global__ void k_swiglu(const float* __restrict__ hidden, bf16* __restrict__ hb) {
    int idx = blockIdx.x * 256 + threadIdx.x; // over S*DFF
    int s = idx / DFF, f = idx % DFF;
    const float* row = hidden + (long)s * (2 * DFF);
    float gv = row[f], av = row[DFF + f];
    float sig = 1.0f / (1.0f + __expf(-gv));
    hb[(long)s * DFF + f] = (bf16)(gv * sig * av);
}

extern "C" void kernel_launch(void* const* d_in, const int* in_sizes, int n_in,
                              void* d_out, int out_size, void* d_ws, size_t ws_size,
                              hipStream_t stream) {
    const int*   ids    = (const int*)d_in[0];
    const float* emb    = (const float*)d_in[1];
    const float* slopes = (const float*)d_in[2];
    const float* ln1_g  = (const float*)d_in[3];
    const float* ln1_b  = (const float*)d_in[4];
    const float* qkv_W  = (const float*)d_in[5];
    const float* qkv_A  = (const float*)d_in[6];
    const float* qkv_B  = (const float*)d_in[7];
    const float* out_W  = (const float*)d_in[8];
    const float* out_A  = (const float*)d_in[9];
    const float* out_B  = (const float*)d_in[10];
    const float* ln2_g  = (const float*)d_in[11];
    const float* ln2_b  = (const float*)d_in[12];
    const float* fc1_W  = (const float*)d_in[13];
    const float* fc1_A  = (const float*)d_in[14];
    const float* fc1_B  = (const float*)d_in[15];
    const float* fc2_W  = (const float*)d_in[16];
    const float* fc2_A  = (const float*)d_in[17];
    const float* fc2_B  = (const float*)d_in[18];
    const float* ls1    = (const float*)d_in[19];
    const float* ls2    = (const float*)d_in[20];
    const float* lnf_g  = (const float*)d_in[21];
    const float* lnf_b  = (const float*)d_in[22];

    // ---- workspace layout ----
    char* p = (char*)d_ws;
    float* x      = (float*)p;               p += (long)S * D * 4;
    float* qkv    = (float*)p;               p += (long)S * 3 * D * 4;
    float* proj   = (float*)p;               p += (long)S * D * 4;
    float* t      = (float*)p;               p += (long)S * R * 4;
    float* hidden = (float*)p;               p += (long)S * 2 * DFF * 4;
    bf16* h_bf    = (bf16*)p;                p += (long)S * D * 2;
    bf16* ao_bf   = (bf16*)p;                p += (long)S * D * 2;
    bf16* hid_bf  = (bf16*)p;                p += (long)S * DFF * 2;
    bf16* emb_bf  = (bf16*)p;                p += (long)V * D * 2;
    bf16* qkvW_bf = (bf16*)p;                p += (long)NLAYERS * 3 * D * D * 2;
    bf16* outW_bf = (bf16*)p;                p += (long)NLAYERS * D * D * 2;
    bf16* fc1W_bf = (bf16*)p;                p += (long)NLAYERS * 2 * DFF * D * 2;
    bf16* fc2W_bf = (bf16*)p;                p += (long)NLAYERS * D * DFF * 2;

    // ---- weight conversions (per launch; ~60us total) ----
    {
        long n;
        n = (long)V * D;
        k_cvt<<<(n / 4 + 255) / 256, 256, 0, stream>>>(emb, emb_bf, n);
        n = (long)NLAYERS * 3 * D * D;
        k_cvt<<<(n / 4 + 255) / 256, 256, 0, stream>>>(qkv_W, qkvW_bf, n);
        n = (long)NLAYERS * D * D;
        k_cvt<<<(n / 4 + 255) / 256, 256, 0, stream>>>(out_W, outW_bf, n);
        n = (long)NLAYERS * 2 * DFF * D;
        k_cvt<<<(n / 4 + 255) / 256, 256, 0, stream>>>(fc1_W, fc1W_bf, n);
        n = (long)NLAYERS * D * DFF;
        k_cvt<<<(n / 4 + 255) / 256, 256, 0, stream>>>(fc2_W, fc2W_bf, n);
    }

    k_embed<<<S, 256, 0, stream>>>(ids, emb, x);

    for (int l = 0; l < NLAYERS; l++) {
        // ---- attention block ----
        k_ln_bf<<<S, 256, 0, stream>>>(x, ln1_g + l * D, ln1_b + l * D, h_bf);
        k_gemm_bf<<<dim3(3 * D / 128, S / 128), 256, 0, stream>>>(h_bf, qkvW_bf + (long)l * 3 * D * D, qkv, 3 * D, D);
        k_lora_t<<<S / 8, 256, 0, stream>>>(h_bf, D, qkv_A + (long)l * D * R, t);
        k_lora_add<<<dim3(3 * D / 256, S), 256, 0, stream>>>(t, qkv_B + (long)l * R * 3 * D, qkv, 3 * D);
        k_attn<<<dim3(S / 4, H), 256, 0, stream>>>(qkv, slopes, ao_bf);
        k_gemm_bf<<<dim3(D / 128, S / 128), 256, 0, stream>>>(ao_bf, outW_bf + (long)l * D * D, proj, D, D);
        k_lora_t<<<S / 8, 256, 0, stream>>>(ao_bf, D, out_A + (long)l * D * R, t);
        k_lora_add<<<dim3(D / 256, S), 256, 0, stream>>>(t, out_B + (long)l * R * D, proj, D);
        k_resid<<<S * D / 256, 256, 0, stream>>>(x, proj, ls1 + l * D);

        // ---- FFN block ----
        k_ln_bf<<<S, 256, 0, stream>>>(x, ln2_g + l * D, ln2_b + l * D, h_bf);
        k_gemm_bf<<<dim3(2 * DFF / 128, S / 128), 256, 0, stream>>>(h_bf, fc1W_bf + (long)l * 2 * DFF * D, hidden, 2 * DFF, D);
        k_lora_t<<<S / 8, 256, 0, stream>>>(h_bf, D, fc1_A + (long)l * D * R, t);
        k_lora_add<<<dim3(2 * DFF / 256, S), 256, 0, stream>>>(t, fc1_B + (long)l * R * 2 * DFF, hidden, 2 * DFF);
        k_swiglu<<<S * DFF / 256, 256, 0, stream>>>(hidden, hid_bf);
        k_gemm_bf<<<dim3(D / 128, S / 128), 256, 0, stream>>>(hid_bf, fc2W_bf + (long)l * D * DFF, proj, D, DFF);
        k_lora_t<<<S / 8, 256, 0, stream>>>(hid_bf, DFF, fc2_A + (long)l * DFF * R, t);
        k_lora_add<<<dim3(D / 256, S), 256, 0, stream>>>(t, fc2_B + (long)l * R * D, proj, D);
        k_resid<<<S * D / 256, 256, 0, stream>>>(x, proj, ls2 + l * D);
    }

    // ---- final LN + tied lm_head ----
    k_ln_bf<<<S, 256, 0, stream>>>(x, lnf_g, lnf_b, h_bf);
    k_gemm_bf<<<dim3(V / 128, S / 128), 256, 0, stream>>>(h_bf, emb_bf, (float*)d_out, V, D);
}

// Round 3
// 3626.427 us; speedup vs baseline: 2.9951x; 2.0775x over previous
//
#include <hip/hip_runtime.h>
#include <hip/hip_bf16.h>
#include <stdint.h>

#define S 2048
#define D 768
#define H 12
#define HD 64
#define V 32000
#define R 32
#define DFF 3072
#define NLAYERS 4
#define EPS 1e-6f

typedef __bf16 bf16;
typedef __bf16 bf16x4 __attribute__((ext_vector_type(4)));
typedef __bf16 bf16x8 __attribute__((ext_vector_type(8)));
typedef float f32x4 __attribute__((ext_vector_type(4)));

// ---------------- fp32 -> bf16 conversion (4 elems/thread) ----------------
__global__ __launch_bounds__(256) void k_cvt(const float* __restrict__ in,
                                             bf16* __restrict__ out, long n) {
    long i = ((long)blockIdx.x * 256 + threadIdx.x) * 4;
    if (i >= n) return;
    float4 v = *(const float4*)(in + i);
    bf16x4 o;
    o.x = (bf16)v.x; o.y = (bf16)v.y; o.z = (bf16)v.z; o.w = (bf16)v.w;
    *(bf16x4*)(out + i) = o;
}

// ---------------- embedding gather ----------------
__global__ void k_embed(const int* __restrict__ ids, const float* __restrict__ emb,
                        float* __restrict__ x) {
    int s = blockIdx.x;
    int row = ids[s];
    for (int d = threadIdx.x; d < D; d += blockDim.x)
        x[s * D + d] = emb[row * D + d];
}

// ---------------- layernorm -> bf16 out (one row per block, 256 thr) -------
__global__ __launch_bounds__(256) void k_ln_bf(const float* __restrict__ x,
                                               const float* __restrict__ g,
                                               const float* __restrict__ b,
                                               bf16* __restrict__ out) {
    int s = blockIdx.x;
    int t = threadIdx.x;
    const float* xr = x + s * D;
    float e0 = xr[t], e1 = xr[t + 256], e2 = xr[t + 512];
    float sum = e0 + e1 + e2;
    float sq = e0 * e0 + e1 * e1 + e2 * e2;
    #pragma unroll
    for (int m = 1; m < 64; m <<= 1) {
        sum += __shfl_xor(sum, m);
        sq  += __shfl_xor(sq, m);
    }
    __shared__ float ssum[4], ssq[4];
    int w = t >> 6;
    if ((t & 63) == 0) { ssum[w] = sum; ssq[w] = sq; }
    __syncthreads();
    sum = ssum[0] + ssum[1] + ssum[2] + ssum[3];
    sq  = ssq[0] + ssq[1] + ssq[2] + ssq[3];
    float mean = sum * (1.0f / D);
    float var  = sq * (1.0f / D) - mean * mean;
    float rs = rsqrtf(var + EPS);
    bf16* orow = out + (long)s * D;
    orow[t]       = (bf16)((e0 - mean) * rs * g[t]       + b[t]);
    orow[t + 256] = (bf16)((e1 - mean) * rs * g[t + 256] + b[t + 256]);
    orow[t + 512] = (bf16)((e2 - mean) * rs * g[t + 512] + b[t + 512]);
}

// ---------------- bf16 MFMA GEMM: C[M,N] = X[M,K] @ W[N,K]^T (fp32 out) ----
__device__ __forceinline__ void gload16(const bf16* g, bf16* l) {
    __builtin_amdgcn_global_load_lds(
        (const __attribute__((address_space(1))) void*)g,
        (__attribute__((address_space(3))) void*)l, 16, 0, 0);
}

__global__ __launch_bounds__(256) void k_gemm_bf(const bf16* __restrict__ X,
                                                 const bf16* __restrict__ W,
                                                 float* __restrict__ C,
                                                 int N, int K) {
    __shared__ bf16 At[128 * 32];
    __shared__ bf16 Bt[128 * 32];
    int tid = threadIdx.x;
    int w = tid >> 6, lane = tid & 63;
    long m0 = (long)blockIdx.y * 128, n0 = (long)blockIdx.x * 128;
    int wr = (w >> 1) * 64, wc = (w & 1) * 64;
    int c0 = w, c1 = w + 4;
    int rA0 = c0 * 16 + (lane >> 2);
    int rA1 = c1 * 16 + (lane >> 2);
    int ck = (lane & 3) * 8;
    int fr = lane & 15;
    int fo = (lane >> 4) * 8;
    f32x4 acc[4][4] = {};
    for (int k0 = 0; k0 < K; k0 += 32) {
        gload16(X + (m0 + rA0) * K + k0 + ck, At + c0 * 512);
        gload16(X + (m0 + rA1) * K + k0 + ck, At + c1 * 512);
        gload16(W + (n0 + rA0) * K + k0 + ck, Bt + c0 * 512);
        gload16(W + (n0 + rA1) * K + k0 + ck, Bt + c1 * 512);
        __syncthreads();
        bf16x8 a[4], b[4];
        #pragma unroll
        for (int m = 0; m < 4; m++)
            a[m] = *(const bf16x8*)(At + (wr + m * 16 + fr) * 32 + fo);
        #pragma unroll
        for (int n = 0; n < 4; n++)
            b[n] = *(const bf16x8*)(Bt + (wc + n * 16 + fr) * 32 + fo);
        #pragma unroll
        for (int m = 0; m < 4; m++)
            #pragma unroll
            for (int n = 0; n < 4; n++)
                acc[m][n] = __builtin_amdgcn_mfma_f32_16x16x32_bf16(a[m], b[n], acc[m][n], 0, 0, 0);
        __syncthreads();
    }
    int cr = (lane >> 4) * 4, cc = lane & 15;
    #pragma unroll
    for (int m = 0; m < 4; m++)
        #pragma unroll
        for (int n = 0; n < 4; n++)
            #pragma unroll
            for (int r = 0; r < 4; r++)
                C[(m0 + wr + m * 16 + cr + r) * N + n0 + wc + n * 16 + cc] = acc[m][n][r];
}

// ---------------- LoRA: T[M,R] = Xbf[M,K] @ A[K,R] ----------------
__global__ __launch_bounds__(256) void k_lora_t(const bf16* __restrict__ X, int K,
                                                const float* __restrict__ A,
                                                float* __restrict__ T) {
    int m = blockIdx.x * 8 + (threadIdx.x >> 5);
    int r = threadIdx.x & 31;
    const bf16* xr = X + (long)m * K;
    float s0 = 0.f, s1 = 0.f, s2 = 0.f, s3 = 0.f;
    for (int k = 0; k < K; k += 4) {
        s0 += (float)xr[k + 0] * A[(k + 0) * R + r];
        s1 += (float)xr[k + 1] * A[(k + 1) * R + r];
        s2 += (float)xr[k + 2] * A[(k + 2) * R + r];
        s3 += (float)xr[k + 3] * A[(k + 3) * R + r];
    }
    T[m * R + r] = (s0 + s1) + (s2 + s3);
}

// ---------------- LoRA add: C[M,N] += (1/R) * T[M,R] @ B[R,N] ----------------
__global__ __launch_bounds__(256) void k_lora_add(const float* __restrict__ T,
                                                  const float* __restrict__ B,
                                                  float* __restrict__ C, int N) {
    int n = blockIdx.x * 256 + threadIdx.x;
    int m = blockIdx.y;
    const float* tr = T + m * R;
    float sum = 0.f;
    #pragma unroll
    for (int r = 0; r < R; r++) sum += tr[r] * B[r * N + n];
    C[(long)m * N + n] += sum * (1.0f / R);
}

// ---------------- qkv split: fp32 [S][3][H][HD] -> bf16 Qh/Kh [H][S][HD] ----
__global__ __launch_bounds__(256) void k_qkv_prep(const float* __restrict__ qkv,
                                                  bf16* __restrict__ Qh,
                                                  bf16* __restrict__ Kh) {
    int s = blockIdx.x;
    int tid = threadIdx.x;
    const float* row = qkv + (long)s * (3 * D);
    #pragma unroll
    for (int it = 0; it < 3; ++it) {
        int idx = it * 256 + tid;           // 0..767
        int h = idx >> 6, d = idx & 63;
        Qh[((long)h * S + s) * HD + d] = (bf16)(row[idx] * 0.125f);  // fold 1/sqrt(64)
        Kh[((long)h * S + s) * HD + d] = (bf16)(row[768 + idx]);
    }
}

// ---------------- V transpose: fp32 qkv -> bf16 Vt [H][HD][S] ----------------
__global__ __launch_bounds__(256) void k_vtrans(const float* __restrict__ qkv,
                                                bf16* __restrict__ Vt) {
    __shared__ float tile[64][65];
    int s0 = blockIdx.x * 64, h = blockIdx.y;
    int tid = threadIdx.x;
    int r = tid >> 2, c0 = (tid & 3) * 16;
    const float* src = qkv + (long)(s0 + r) * (3 * D) + 2 * D + h * HD + c0;
    #pragma unroll
    for (int i = 0; i < 16; i += 4) {
        float4 v = *(const float4*)(src + i);
        tile[r][c0 + i] = v.x; tile[r][c0 + i + 1] = v.y;
        tile[r][c0 + i + 2] = v.z; tile[r][c0 + i + 3] = v.w;
    }
    __syncthreads();
    int d = tid >> 2, sm0 = (tid & 3) * 16;
    bf16x8 o0, o1;
    #pragma unroll
    for (int m = 0; m < 8; ++m) {
        o0[m] = (bf16)tile[sm0 + m][d];
        o1[m] = (bf16)tile[sm0 + 8 + m][d];
    }
    bf16* dst = Vt + ((long)h * HD + d) * S + s0 + sm0;
    *(bf16x8*)(dst) = o0;
    *(bf16x8*)(dst + 8) = o1;
}

// ---------------- flash attention, MFMA, ALiBi+causal ----------------
// grid (S/64, H), 256 thr = 4 waves; wave w owns q rows [q0+16w, +16).
// Swapped operands: scores C[j][q], PV C[d][q] so softmax stats are lane-local.
// K/V LDS tiles use chunk-XOR swizzle (source-side + read-side, rule 21).
__global__ __launch_bounds__(256) void k_attn_mfma(const bf16* __restrict__ Qh,
                                                   const bf16* __restrict__ Kh,
                                                   const bf16* __restrict__ Vt,
                                                   const float* __restrict__ slopes,
                                                   bf16* __restrict__ ao) {
    __shared__ bf16 Kl[64 * 64];        // [j][d], swizzled chunks
    __shared__ bf16 Vl[64 * 64];        // [d][j], swizzled chunks
    __shared__ bf16 Pl[4][16 * 72];     // per-wave P[q][j], +8 pad
    int tid = threadIdx.x;
    int w = tid >> 6, lane = tid & 63;
    int fr = lane & 15, g = lane >> 4;
    int qb = gridDim.x - 1 - blockIdx.x;   // longest blocks launch first
    int q0 = qb * 64;
    int h = blockIdx.y;
    int ntiles = qb + 1;
    float slope = slopes[h];

    // Q fragments (rows of Q along k), held in regs for whole kernel
    const bf16* qrow = Qh + ((long)h * S + q0 + w * 16 + fr) * HD;
    bf16x8 qf0 = *(const bf16x8*)(qrow + g * 8);
    bf16x8 qf1 = *(const bf16x8*)(qrow + 32 + g * 8);

    // staging: 512 chunks of 16B per tile, 2 per thread; dest is linear,
    // source column-chunk pre-swizzled: c_src = c ^ (row&7)
    int ci0 = tid, ci1 = tid + 256;
    int r0 = ci0 >> 3, c0s = (ci0 & 7) ^ (r0 & 7);
    int r1 = ci1 >> 3, c1s = (ci1 & 7) ^ (r1 & 7);
    const bf16* Kg = Kh + (long)h * S * HD;
    const bf16* Vg = Vt + (long)h * HD * S;

    float m = -1e9f, l = 0.f;
    f32x4 o[4] = {};
    int qg = q0 + w * 16 + fr;

    for (int t = 0; t < ntiles; ++t) {
        int j0 = t * 64;
        __syncthreads();   // previous tile's reads done
        gload16(Kg + (long)(j0 + r0) * HD + c0s * 8, Kl + ci0 * 8);
        gload16(Kg + (long)(j0 + r1) * HD + c1s * 8, Kl + ci1 * 8);
        gload16(Vg + (long)r0 * S + j0 + c0s * 8, Vl + ci0 * 8);
        gload16(Vg + (long)r1 * S + j0 + c1s * 8, Vl + ci1 * 8);
        __syncthreads();   // compiler drains vmcnt before barrier

        // ---- QK^T: C[j][q], 16x16x32, K rows as A, Q rows as B ----
        f32x4 sc[4];
        #pragma unroll
        for (int jt = 0; jt < 4; ++jt) {
            int jr = jt * 16 + fr;
            bf16x8 kf0 = *(const bf16x8*)(Kl + jr * 64 + ((g ^ (jr & 7)) * 8));
            bf16x8 kf1 = *(const bf16x8*)(Kl + jr * 64 + (((g + 4) ^ (jr & 7)) * 8));
            f32x4 z = {};
            z = __builtin_amdgcn_mfma_f32_16x16x32_bf16(kf0, qf0, z, 0, 0, 0);
            z = __builtin_amdgcn_mfma_f32_16x16x32_bf16(kf1, qf1, z, 0, 0, 0);
            sc[jt] = z;
        }
        // ---- mask + ALiBi + online softmax (per lane: q = fr) ----
        float s[4][4];
        float mt = -1e9f;
        #pragma unroll
        for (int jt = 0; jt < 4; ++jt)
            #pragma unroll
            for (int r = 0; r < 4; ++r) {
                int jg = j0 + jt * 16 + g * 4 + r;
                int rel = jg - qg;
                float v = (rel <= 0) ? fmaf(slope, (float)rel, sc[jt][r]) : -1e9f;
                s[jt][r] = v;
                mt = fmaxf(mt, v);
            }
        mt = fmaxf(mt, __shfl_xor(mt, 16));
        mt = fmaxf(mt, __shfl_xor(mt, 32));
        float mnew = fmaxf(m, mt);
        float factor = __expf(m - mnew);
        float psum = 0.f;
        #pragma unroll
        for (int jt = 0; jt < 4; ++jt) {
            bf16x4 pb;
            #pragma unroll
            for (int r = 0; r < 4; ++r) {
                float p = __expf(s[jt][r] - mnew);
                psum += p;
                pb[r] = (bf16)p;
            }
            *(bf16x4*)(&Pl[w][fr * 72 + jt * 16 + g * 4]) = pb;
        }
        psum += __shfl_xor(psum, 16);
        psum += __shfl_xor(psum, 32);
        l = l * factor + psum;
        m = mnew;
        #pragma unroll
        for (int dt = 0; dt < 4; ++dt)
            #pragma unroll
            for (int r = 0; r < 4; ++r) o[dt][r] *= factor;

        // ---- PV: C[d][q], Vt rows as A, P rows as B ----
        bf16x8 pf0 = *(const bf16x8*)(&Pl[w][fr * 72 + g * 8]);
        bf16x8 pf1 = *(const bf16x8*)(&Pl[w][fr * 72 + 32 + g * 8]);
        #pragma unroll
        for (int dt = 0; dt < 4; ++dt) {
            int dr = dt * 16 + fr;
            bf16x8 vf0 = *(const bf16x8*)(Vl + dr * 64 + ((g ^ (dr & 7)) * 8));
            bf16x8 vf1 = *(const bf16x8*)(Vl + dr * 64 + (((g + 4) ^ (dr & 7)) * 8));
            o[dt] = __builtin_amdgcn_mfma_f32_16x16x32_bf16(vf0, pf0, o[dt], 0, 0, 0);
            o[dt] = __builtin_amdgcn_mfma_f32_16x16x32_bf16(vf1, pf1, o[dt], 0, 0, 0);
        }
    }
    // ---- epilogue: q = fr, d = dt*16 + g*4 + r ----
    float inv = 1.0f / l;
    bf16* orow = ao + ((long)(q0 + w * 16 + fr)) * D + h * HD;
    #pragma unroll
    for (int dt = 0; dt < 4; ++dt) {
        bf16x4 ob;
        #pragma unroll
        for (int r = 0; r < 4; ++r) ob[r] = (bf16)(o[dt][r] * inv);
        *(bf16x4*)(orow + dt * 16 + g * 4) = ob;
    }
}

// ---------------- residual with LayerScale: x += ls * y ----------------
__global__ void k_resid(float* __restrict__ x, const float* __restrict__ y,
                        const float* __restrict__ ls) {
    int idx = blockIdx.x * 256 + threadIdx.x;
    x[idx] += ls[idx % D] * y[idx];
}

// ---------------- SwiGLU: hb[s,f] = silu(g) * a  (bf16 out) ----------------
__global__ void k_swiglu(const float* __restrict__ hidden, bf16* __restrict__ hb) {
    int idx = blockIdx.x * 256 + threadIdx.x; // over S*DFF
    int s = idx / DFF, f = idx % DFF;
    const float* row = hidden + (long)s * (2 * DFF);
    float gv = row[f], av = row[DFF + f];
    float sig = 1.0f / (1.0f + __expf(-gv));
    hb[(long)s * DFF + f] = (bf16)(gv * sig * av);
}

extern "C" void kernel_launch(void* const* d_in, const int* in_sizes, int n_in,
                              void* d_out, int out_size, void* d_ws, size_t ws_size,
                              hipStream_t stream) {
    const int*   ids    = (const int*)d_in[0];
    const float* emb    = (const float*)d_in[1];
    const float* slopes = (const float*)d_in[2];
    const float* ln1_g  = (const float*)d_in[3];
    const float* ln1_b  = (const float*)d_in[4];
    const float* qkv_W  = (const float*)d_in[5];
    const float* qkv_A  = (const float*)d_in[6];
    const float* qkv_B  = (const float*)d_in[7];
    const float* out_W  = (const float*)d_in[8];
    const float* out_A  = (const float*)d_in[9];
    const float* out_B  = (const float*)d_in[10];
    const float* ln2_g  = (const float*)d_in[11];
    const float* ln2_b  = (const float*)d_in[12];
    const float* fc1_W  = (const float*)d_in[13];
    const float* fc1_A  = (const float*)d_in[14];
    const float* fc1_B  = (const float*)d_in[15];
    const float* fc2_W  = (const float*)d_in[16];
    const float* fc2_A  = (const float*)d_in[17];
    const float* fc2_B  = (const float*)d_in[18];
    const float* ls1    = (const float*)d_in[19];
    const float* ls2    = (const float*)d_in[20];
    const float* lnf_g  = (const float*)d_in[21];
    const float* lnf_b  = (const float*)d_in[22];

    // ---- workspace layout ----
    char* p = (char*)d_ws;
    float* x      = (float*)p;               p += (long)S * D * 4;
    float* qkv    = (float*)p;               p += (long)S * 3 * D * 4;
    float* proj   = (float*)p;               p += (long)S * D * 4;
    float* t      = (float*)p;               p += (long)S * R * 4;
    float* hidden = (float*)p;               p += (long)S * 2 * DFF * 4;
    bf16* h_bf    = (bf16*)p;                p += (long)S * D * 2;
    bf16* ao_bf   = (bf16*)p;                p += (long)S * D * 2;
    bf16* hid_bf  = (bf16*)p;                p += (long)S * DFF * 2;
    bf16* Qh      = (bf16*)p;                p += (long)H * S * HD * 2;
    bf16* Kh      = (bf16*)p;                p += (long)H * S * HD * 2;
    bf16* Vt      = (bf16*)p;                p += (long)H * HD * S * 2;
    bf16* emb_bf  = (bf16*)p;                p += (long)V * D * 2;
    bf16* qkvW_bf = (bf16*)p;                p += (long)NLAYERS * 3 * D * D * 2;
    bf16* outW_bf = (bf16*)p;                p += (long)NLAYERS * D * D * 2;
    bf16* fc1W_bf = (bf16*)p;                p += (long)NLAYERS * 2 * DFF * D * 2;
    bf16* fc2W_bf = (bf16*)p;                p += (long)NLAYERS * D * DFF * 2;

    // ---- weight conversions ----
    {
        long n;
        n = (long)V * D;
        k_cvt<<<(n / 4 + 255) / 256, 256, 0, stream>>>(emb, emb_bf, n);
        n = (long)NLAYERS * 3 * D * D;
        k_cvt<<<(n / 4 + 255) / 256, 256, 0, stream>>>(qkv_W, qkvW_bf, n);
        n = (long)NLAYERS * D * D;
        k_cvt<<<(n / 4 + 255) / 256, 256, 0, stream>>>(out_W, outW_bf, n);
        n = (long)NLAYERS * 2 * DFF * D;
        k_cvt<<<(n / 4 + 255) / 256, 256, 0, stream>>>(fc1_W, fc1W_bf, n);
        n = (long)NLAYERS * D * DFF;
        k_cvt<<<(n / 4 + 255) / 256, 256, 0, stream>>>(fc2_W, fc2W_bf, n);
    }

    k_embed<<<S, 256, 0, stream>>>(ids, emb, x);

    for (int l = 0; l < NLAYERS; l++) {
        // ---- attention block ----
        k_ln_bf<<<S, 256, 0, stream>>>(x, ln1_g + l * D, ln1_b + l * D, h_bf);
        k_gemm_bf<<<dim3(3 * D / 128, S / 128), 256, 0, stream>>>(h_bf, qkvW_bf + (long)l * 3 * D * D, qkv, 3 * D, D);
        k_lora_t<<<S / 8, 256, 0, stream>>>(h_bf, D, qkv_A + (long)l * D * R, t);
        k_lora_add<<<dim3(3 * D / 256, S), 256, 0, stream>>>(t, qkv_B + (long)l * R * 3 * D, qkv, 3 * D);
        k_qkv_prep<<<S, 256, 0, stream>>>(qkv, Qh, Kh);
        k_vtrans<<<dim3(S / 64, H), 256, 0, stream>>>(qkv, Vt);
        k_attn_mfma<<<dim3(S / 64, H), 256, 0, stream>>>(Qh, Kh, Vt, slopes, ao_bf);
        k_gemm_bf<<<dim3(D / 128, S / 128), 256, 0, stream>>>(ao_bf, outW_bf + (long)l * D * D, proj, D, D);
        k_lora_t<<<S / 8, 256, 0, stream>>>(ao_bf, D, out_A + (long)l * D * R, t);
        k_lora_add<<<dim3(D / 256, S), 256, 0, stream>>>(t, out_B + (long)l * R * D, proj, D);
        k_resid<<<S * D / 256, 256, 0, stream>>>(x, proj, ls1 + l * D);

        // ---- FFN block ----
        k_ln_bf<<<S, 256, 0, stream>>>(x, ln2_g + l * D, ln2_b + l * D, h_bf);
        k_gemm_bf<<<dim3(2 * DFF / 128, S / 128), 256, 0, stream>>>(h_bf, fc1W_bf + (long)l * 2 * DFF * D, hidden, 2 * DFF, D);
        k_lora_t<<<S / 8, 256, 0, stream>>>(h_bf, D, fc1_A + (long)l * D * R, t);
        k_lora_add<<<dim3(2 * DFF / 256, S), 256, 0, stream>>>(t, fc1_B + (long)l * R * 2 * DFF, hidden, 2 * DFF);
        k_swiglu<<<S * DFF / 256, 256, 0, stream>>>(hidden, hid_bf);
        k_gemm_bf<<<dim3(D / 128, S / 128), 256, 0, stream>>>(hid_bf, fc2W_bf + (long)l * D * DFF, proj, D, DFF);
        k_lora_t<<<S / 8, 256, 0, stream>>>(hid_bf, DFF, fc2_A + (long)l * DFF * R, t);
        k_lora_add<<<dim3(D / 256, S), 256, 0, stream>>>(t, fc2_B + (long)l * R * D, proj, D);
        k_resid<<<S * D / 256, 256, 0, stream>>>(x, proj, ls2 + l * D);
    }

    // ---- final LN + tied lm_head ----
    k_ln_bf<<<S, 256, 0, stream>>>(x, lnf_g, lnf_b, h_bf);
    k_gemm_bf<<<dim3(V / 128, S / 128), 256, 0, stream>>>(h_bf, emb_bf, (float*)d_out, V, D);
}

// Round 4
// 1379.702 us; speedup vs baseline: 7.8723x; 2.6284x over previous
//
#include <hip/hip_runtime.h>
#include <hip/hip_bf16.h>
#include <stdint.h>

#define S 2048
#define D 768
#define H 12
#define HD 64
#define V 32000
#define R 32
#define DFF 3072
#define NLAYERS 4
#define EPS 1e-6f

typedef __bf16 bf16;
typedef __bf16 bf16x4 __attribute__((ext_vector_type(4)));
typedef __bf16 bf16x8 __attribute__((ext_vector_type(8)));
typedef float f32x4 __attribute__((ext_vector_type(4)));

// ---------------- fp32 -> bf16 conversion (4 elems/thread) ----------------
__global__ __launch_bounds__(256) void k_cvt(const float* __restrict__ in,
                                             bf16* __restrict__ out, long n) {
    long i = ((long)blockIdx.x * 256 + threadIdx.x) * 4;
    if (i >= n) return;
    float4 v = *(const float4*)(in + i);
    bf16x4 o;
    o.x = (bf16)v.x; o.y = (bf16)v.y; o.z = (bf16)v.z; o.w = (bf16)v.w;
    *(bf16x4*)(out + i) = o;
}

// ---------------- A transpose: A[l][K][R] -> At[l][R][K] ----------------
__global__ __launch_bounds__(256) void k_atrans(const float* __restrict__ A,
                                                float* __restrict__ At, int K) {
    int idx = blockIdx.x * 256 + threadIdx.x;   // over NLAYERS*R*K
    int l = idx / (R * K);
    int j = idx % (R * K);
    int r = j / K, k = j % K;
    At[idx] = A[(long)l * K * R + (long)k * R + r];
}

// ---- LoRA fold: Wb[n,k] = bf16( W[n,k] + (1/R) * sum_r At[r,k]*B[r,n] ) ----
// grid (K/256, N/8, NLAYERS); threads along k (coalesced).
__global__ __launch_bounds__(256) void k_fold(const float* __restrict__ W,
                                              const float* __restrict__ At,
                                              const float* __restrict__ B,
                                              bf16* __restrict__ Wb,
                                              int N, int K) {
    int l = blockIdx.z;
    const float* Wl  = W  + (long)l * N * K;
    const float* Atl = At + (long)l * R * K;
    const float* Bl  = B  + (long)l * R * N;
    bf16* Wbl = Wb + (long)l * N * K;
    int k = blockIdx.x * 256 + threadIdx.x;
    int n0 = blockIdx.y * 8;
    float acc[8];
    #pragma unroll
    for (int j = 0; j < 8; ++j) acc[j] = Wl[(long)(n0 + j) * K + k];
    for (int r = 0; r < R; ++r) {
        float a = Atl[(long)r * K + k] * (1.0f / R);
        #pragma unroll
        for (int j = 0; j < 8; ++j)
            acc[j] = fmaf(a, Bl[(long)r * N + n0 + j], acc[j]);
    }
    #pragma unroll
    for (int j = 0; j < 8; ++j) Wbl[(long)(n0 + j) * K + k] = (bf16)acc[j];
}

// ---------------- embedding gather ----------------
__global__ void k_embed(const int* __restrict__ ids, const float* __restrict__ emb,
                        float* __restrict__ x) {
    int s = blockIdx.x;
    int row = ids[s];
    for (int d = threadIdx.x; d < D; d += blockDim.x)
        x[s * D + d] = emb[row * D + d];
}

// ---------------- layernorm -> bf16 out (one row per block, 256 thr) -------
__global__ __launch_bounds__(256) void k_ln_bf(const float* __restrict__ x,
                                               const float* __restrict__ g,
                                               const float* __restrict__ b,
                                               bf16* __restrict__ out) {
    int s = blockIdx.x;
    int t = threadIdx.x;
    const float* xr = x + s * D;
    float e0 = xr[t], e1 = xr[t + 256], e2 = xr[t + 512];
    float sum = e0 + e1 + e2;
    float sq = e0 * e0 + e1 * e1 + e2 * e2;
    #pragma unroll
    for (int m = 1; m < 64; m <<= 1) {
        sum += __shfl_xor(sum, m);
        sq  += __shfl_xor(sq, m);
    }
    __shared__ float ssum[4], ssq[4];
    int w = t >> 6;
    if ((t & 63) == 0) { ssum[w] = sum; ssq[w] = sq; }
    __syncthreads();
    sum = ssum[0] + ssum[1] + ssum[2] + ssum[3];
    sq  = ssq[0] + ssq[1] + ssq[2] + ssq[3];
    float mean = sum * (1.0f / D);
    float var  = sq * (1.0f / D) - mean * mean;
    float rs = rsqrtf(var + EPS);
    bf16* orow = out + (long)s * D;
    orow[t]       = (bf16)((e0 - mean) * rs * g[t]       + b[t]);
    orow[t + 256] = (bf16)((e1 - mean) * rs * g[t + 256] + b[t + 256]);
    orow[t + 512] = (bf16)((e2 - mean) * rs * g[t + 512] + b[t + 512]);
}

// ---------------- bf16 MFMA GEMM: C[M,N] = X[M,K] @ W[N,K]^T ----------------
// RESID=false: C = acc (fp32).  RESID=true: C[m,n] += ls[n]*acc (in place).
__device__ __forceinline__ void gload16(const bf16* g, bf16* l) {
    __builtin_amdgcn_global_load_lds(
        (const __attribute__((address_space(1))) void*)g,
        (__attribute__((address_space(3))) void*)l, 16, 0, 0);
}

template <bool RESID>
__global__ __launch_bounds__(256) void k_gemm_bf(const bf16* __restrict__ X,
                                                 const bf16* __restrict__ W,
                                                 float* __restrict__ C,
                                                 int N, int K,
                                                 const float* __restrict__ ls) {
    __shared__ bf16 At[128 * 32];
    __shared__ bf16 Bt[128 * 32];
    int tid = threadIdx.x;
    int w = tid >> 6, lane = tid & 63;
    long m0 = (long)blockIdx.y * 128, n0 = (long)blockIdx.x * 128;
    int wr = (w >> 1) * 64, wc = (w & 1) * 64;
    int c0 = w, c1 = w + 4;
    int rA0 = c0 * 16 + (lane >> 2);
    int rA1 = c1 * 16 + (lane >> 2);
    int ck = (lane & 3) * 8;
    int fr = lane & 15;
    int fo = (lane >> 4) * 8;
    f32x4 acc[4][4] = {};
    for (int k0 = 0; k0 < K; k0 += 32) {
        gload16(X + (m0 + rA0) * K + k0 + ck, At + c0 * 512);
        gload16(X + (m0 + rA1) * K + k0 + ck, At + c1 * 512);
        gload16(W + (n0 + rA0) * K + k0 + ck, Bt + c0 * 512);
        gload16(W + (n0 + rA1) * K + k0 + ck, Bt + c1 * 512);
        __syncthreads();
        bf16x8 a[4], b[4];
        #pragma unroll
        for (int m = 0; m < 4; m++)
            a[m] = *(const bf16x8*)(At + (wr + m * 16 + fr) * 32 + fo);
        #pragma unroll
        for (int n = 0; n < 4; n++)
            b[n] = *(const bf16x8*)(Bt + (wc + n * 16 + fr) * 32 + fo);
        #pragma unroll
        for (int m = 0; m < 4; m++)
            #pragma unroll
            for (int n = 0; n < 4; n++)
                acc[m][n] = __builtin_amdgcn_mfma_f32_16x16x32_bf16(a[m], b[n], acc[m][n], 0, 0, 0);
        __syncthreads();
    }
    int cr = (lane >> 4) * 4, cc = lane & 15;
    #pragma unroll
    for (int m = 0; m < 4; m++)
        #pragma unroll
        for (int n = 0; n < 4; n++) {
            long col = n0 + wc + n * 16 + cc;
            #pragma unroll
            for (int r = 0; r < 4; r++) {
                long idx = (m0 + wr + m * 16 + cr + r) * N + col;
                if (RESID)
                    C[idx] = fmaf(ls[col], acc[m][n][r], C[idx]);
                else
                    C[idx] = acc[m][n][r];
            }
        }
}

// ---------------- qkv split: fp32 [S][3][H][HD] -> bf16 Qh/Kh [H][S][HD] ----
__global__ __launch_bounds__(256) void k_qkv_prep(const float* __restrict__ qkv,
                                                  bf16* __restrict__ Qh,
                                                  bf16* __restrict__ Kh) {
    int s = blockIdx.x;
    int tid = threadIdx.x;
    const float* row = qkv + (long)s * (3 * D);
    #pragma unroll
    for (int it = 0; it < 3; ++it) {
        int idx = it * 256 + tid;           // 0..767
        int h = idx >> 6, d = idx & 63;
        Qh[((long)h * S + s) * HD + d] = (bf16)(row[idx] * 0.125f);  // fold 1/sqrt(64)
        Kh[((long)h * S + s) * HD + d] = (bf16)(row[768 + idx]);
    }
}

// ---------------- V transpose: fp32 qkv -> bf16 Vt [H][HD][S] ----------------
__global__ __launch_bounds__(256) void k_vtrans(const float* __restrict__ qkv,
                                                bf16* __restrict__ Vt) {
    __shared__ float tile[64][65];
    int s0 = blockIdx.x * 64, h = blockIdx.y;
    int tid = threadIdx.x;
    int r = tid >> 2, c0 = (tid & 3) * 16;
    const float* src = qkv + (long)(s0 + r) * (3 * D) + 2 * D + h * HD + c0;
    #pragma unroll
    for (int i = 0; i < 16; i += 4) {
        float4 v = *(const float4*)(src + i);
        tile[r][c0 + i] = v.x; tile[r][c0 + i + 1] = v.y;
        tile[r][c0 + i + 2] = v.z; tile[r][c0 + i + 3] = v.w;
    }
    __syncthreads();
    int d = tid >> 2, sm0 = (tid & 3) * 16;
    bf16x8 o0, o1;
    #pragma unroll
    for (int m = 0; m < 8; ++m) {
        o0[m] = (bf16)tile[sm0 + m][d];
        o1[m] = (bf16)tile[sm0 + 8 + m][d];
    }
    bf16* dst = Vt + ((long)h * HD + d) * S + s0 + sm0;
    *(bf16x8*)(dst) = o0;
    *(bf16x8*)(dst + 8) = o1;
}

// ---------------- flash attention, MFMA, ALiBi+causal ----------------
__global__ __launch_bounds__(256) void k_attn_mfma(const bf16* __restrict__ Qh,
                                                   const bf16* __restrict__ Kh,
                                                   const bf16* __restrict__ Vt,
                                                   const float* __restrict__ slopes,
                                                   bf16* __restrict__ ao) {
    __shared__ bf16 Kl[64 * 64];
    __shared__ bf16 Vl[64 * 64];
    __shared__ bf16 Pl[4][16 * 72];
    int tid = threadIdx.x;
    int w = tid >> 6, lane = tid & 63;
    int fr = lane & 15, g = lane >> 4;
    int qb = gridDim.x - 1 - blockIdx.x;
    int q0 = qb * 64;
    int h = blockIdx.y;
    int ntiles = qb + 1;
    float slope = slopes[h];

    const bf16* qrow = Qh + ((long)h * S + q0 + w * 16 + fr) * HD;
    bf16x8 qf0 = *(const bf16x8*)(qrow + g * 8);
    bf16x8 qf1 = *(const bf16x8*)(qrow + 32 + g * 8);

    int ci0 = tid, ci1 = tid + 256;
    int r0 = ci0 >> 3, c0s = (ci0 & 7) ^ (r0 & 7);
    int r1 = ci1 >> 3, c1s = (ci1 & 7) ^ (r1 & 7);
    const bf16* Kg = Kh + (long)h * S * HD;
    const bf16* Vg = Vt + (long)h * HD * S;

    float m = -1e9f, l = 0.f;
    f32x4 o[4] = {};
    int qg = q0 + w * 16 + fr;

    for (int t = 0; t < ntiles; ++t) {
        int j0 = t * 64;
        __syncthreads();
        gload16(Kg + (long)(j0 + r0) * HD + c0s * 8, Kl + ci0 * 8);
        gload16(Kg + (long)(j0 + r1) * HD + c1s * 8, Kl + ci1 * 8);
        gload16(Vg + (long)r0 * S + j0 + c0s * 8, Vl + ci0 * 8);
        gload16(Vg + (long)r1 * S + j0 + c1s * 8, Vl + ci1 * 8);
        __syncthreads();

        f32x4 sc[4];
        #pragma unroll
        for (int jt = 0; jt < 4; ++jt) {
            int jr = jt * 16 + fr;
            bf16x8 kf0 = *(const bf16x8*)(Kl + jr * 64 + ((g ^ (jr & 7)) * 8));
            bf16x8 kf1 = *(const bf16x8*)(Kl + jr * 64 + (((g + 4) ^ (jr & 7)) * 8));
            f32x4 z = {};
            z = __builtin_amdgcn_mfma_f32_16x16x32_bf16(kf0, qf0, z, 0, 0, 0);
            z = __builtin_amdgcn_mfma_f32_16x16x32_bf16(kf1, qf1, z, 0, 0, 0);
            sc[jt] = z;
        }
        float s[4][4];
        float mt = -1e9f;
        #pragma unroll
        for (int jt = 0; jt < 4; ++jt)
            #pragma unroll
            for (int r = 0; r < 4; ++r) {
                int jg = j0 + jt * 16 + g * 4 + r;
                int rel = jg - qg;
                float v = (rel <= 0) ? fmaf(slope, (float)rel, sc[jt][r]) : -1e9f;
                s[jt][r] = v;
                mt = fmaxf(mt, v);
            }
        mt = fmaxf(mt, __shfl_xor(mt, 16));
        mt = fmaxf(mt, __shfl_xor(mt, 32));
        float mnew = fmaxf(m, mt);
        float factor = __expf(m - mnew);
        float psum = 0.f;
        #pragma unroll
        for (int jt = 0; jt < 4; ++jt) {
            bf16x4 pb;
            #pragma unroll
            for (int r = 0; r < 4; ++r) {
                float p = __expf(s[jt][r] - mnew);
                psum += p;
                pb[r] = (bf16)p;
            }
            *(bf16x4*)(&Pl[w][fr * 72 + jt * 16 + g * 4]) = pb;
        }
        psum += __shfl_xor(psum, 16);
        psum += __shfl_xor(psum, 32);
        l = l * factor + psum;
        m = mnew;
        #pragma unroll
        for (int dt = 0; dt < 4; ++dt)
            #pragma unroll
            for (int r = 0; r < 4; ++r) o[dt][r] *= factor;

        bf16x8 pf0 = *(const bf16x8*)(&Pl[w][fr * 72 + g * 8]);
        bf16x8 pf1 = *(const bf16x8*)(&Pl[w][fr * 72 + 32 + g * 8]);
        #pragma unroll
        for (int dt = 0; dt < 4; ++dt) {
            int dr = dt * 16 + fr;
            bf16x8 vf0 = *(const bf16x8*)(Vl + dr * 64 + ((g ^ (dr & 7)) * 8));
            bf16x8 vf1 = *(const bf16x8*)(Vl + dr * 64 + (((g + 4) ^ (dr & 7)) * 8));
            o[dt] = __builtin_amdgcn_mfma_f32_16x16x32_bf16(vf0, pf0, o[dt], 0, 0, 0);
            o[dt] = __builtin_amdgcn_mfma_f32_16x16x32_bf16(vf1, pf1, o[dt], 0, 0, 0);
        }
    }
    float inv = 1.0f / l;
    bf16* orow = ao + ((long)(q0 + w * 16 + fr)) * D + h * HD;
    #pragma unroll
    for (int dt = 0; dt < 4; ++dt) {
        bf16x4 ob;
        #pragma unroll
        for (int r = 0; r < 4; ++r) ob[r] = (bf16)(o[dt][r] * inv);
        *(bf16x4*)(orow + dt * 16 + g * 4) = ob;
    }
}

// ---------------- SwiGLU: hb[s,f] = silu(g) * a  (bf16 out) ----------------
__global__ void k_swiglu(const float* __restrict__ hidden, bf16* __restrict__ hb) {
    int idx = blockIdx.x * 256 + threadIdx.x; // over S*DFF
    int s = idx / DFF, f = idx % DFF;
    const float* row = hidden + (long)s * (2 * DFF);
    float gv = row[f], av = row[DFF + f];
    float sig = 1.0f / (1.0f + __expf(-gv));
    hb[(long)s * DFF + f] = (bf16)(gv * sig * av);
}

extern "C" void kernel_launch(void* const* d_in, const int* in_sizes, int n_in,
                              void* d_out, int out_size, void* d_ws, size_t ws_size,
                              hipStream_t stream) {
    const int*   ids    = (const int*)d_in[0];
    const float* emb    = (const float*)d_in[1];
    const float* slopes = (const float*)d_in[2];
    const float* ln1_g  = (const float*)d_in[3];
    const float* ln1_b  = (const float*)d_in[4];
    const float* qkv_W  = (const float*)d_in[5];
    const float* qkv_A  = (const float*)d_in[6];
    const float* qkv_B  = (const float*)d_in[7];
    const float* out_W  = (const float*)d_in[8];
    const float* out_A  = (const float*)d_in[9];
    const float* out_B  = (const float*)d_in[10];
    const float* ln2_g  = (const float*)d_in[11];
    const float* ln2_b  = (const float*)d_in[12];
    const float* fc1_W  = (const float*)d_in[13];
    const float* fc1_A  = (const float*)d_in[14];
    const float* fc1_B  = (const float*)d_in[15];
    const float* fc2_W  = (const float*)d_in[16];
    const float* fc2_A  = (const float*)d_in[17];
    const float* fc2_B  = (const float*)d_in[18];
    const float* ls1    = (const float*)d_in[19];
    const float* ls2    = (const float*)d_in[20];
    const float* lnf_g  = (const float*)d_in[21];
    const float* lnf_b  = (const float*)d_in[22];

    // ---- workspace layout ----
    char* p = (char*)d_ws;
    float* x      = (float*)p;               p += (long)S * D * 4;
    float* qkv    = (float*)p;               p += (long)S * 3 * D * 4;
    float* hidden = (float*)p;               p += (long)S * 2 * DFF * 4;
    bf16* h_bf    = (bf16*)p;                p += (long)S * D * 2;
    bf16* ao_bf   = (bf16*)p;                p += (long)S * D * 2;
    bf16* hid_bf  = (bf16*)p;                p += (long)S * DFF * 2;
    bf16* Qh      = (bf16*)p;                p += (long)H * S * HD * 2;
    bf16* Kh      = (bf16*)p;                p += (long)H * S * HD * 2;
    bf16* Vt      = (bf16*)p;                p += (long)H * HD * S * 2;
    bf16* emb_bf  = (bf16*)p;                p += (long)V * D * 2;
    bf16* qkvW_bf = (bf16*)p;                p += (long)NLAYERS * 3 * D * D * 2;
    bf16* outW_bf = (bf16*)p;                p += (long)NLAYERS * D * D * 2;
    bf16* fc1W_bf = (bf16*)p;                p += (long)NLAYERS * 2 * DFF * D * 2;
    bf16* fc2W_bf = (bf16*)p;                p += (long)NLAYERS * D * DFF * 2;
    float* qkvA_t = (float*)p;               p += (long)NLAYERS * R * D * 4;
    float* outA_t = (float*)p;               p += (long)NLAYERS * R * D * 4;
    float* fc1A_t = (float*)p;               p += (long)NLAYERS * R * D * 4;
    float* fc2A_t = (float*)p;               p += (long)NLAYERS * R * DFF * 4;

    // ---- weight prep: transpose A's, fold LoRA into bf16 weights ----
    k_atrans<<<NLAYERS * R * D / 256, 256, 0, stream>>>(qkv_A, qkvA_t, D);
    k_atrans<<<NLAYERS * R * D / 256, 256, 0, stream>>>(out_A, outA_t, D);
    k_atrans<<<NLAYERS * R * D / 256, 256, 0, stream>>>(fc1_A, fc1A_t, D);
    k_atrans<<<NLAYERS * R * DFF / 256, 256, 0, stream>>>(fc2_A, fc2A_t, DFF);
    k_fold<<<dim3(D / 256, 3 * D / 8, NLAYERS), 256, 0, stream>>>(qkv_W, qkvA_t, qkv_B, qkvW_bf, 3 * D, D);
    k_fold<<<dim3(D / 256, D / 8, NLAYERS), 256, 0, stream>>>(out_W, outA_t, out_B, outW_bf, D, D);
    k_fold<<<dim3(D / 256, 2 * DFF / 8, NLAYERS), 256, 0, stream>>>(fc1_W, fc1A_t, fc1_B, fc1W_bf, 2 * DFF, D);
    k_fold<<<dim3(DFF / 256, D / 8, NLAYERS), 256, 0, stream>>>(fc2_W, fc2A_t, fc2_B, fc2W_bf, D, DFF);
    {
        long n = (long)V * D;
        k_cvt<<<(n / 4 + 255) / 256, 256, 0, stream>>>(emb, emb_bf, n);
    }

    k_embed<<<S, 256, 0, stream>>>(ids, emb, x);

    for (int l = 0; l < NLAYERS; l++) {
        // ---- attention block ----
        k_ln_bf<<<S, 256, 0, stream>>>(x, ln1_g + l * D, ln1_b + l * D, h_bf);
        k_gemm_bf<false><<<dim3(3 * D / 128, S / 128), 256, 0, stream>>>(h_bf, qkvW_bf + (long)l * 3 * D * D, qkv, 3 * D, D, nullptr);
        k_qkv_prep<<<S, 256, 0, stream>>>(qkv, Qh, Kh);
        k_vtrans<<<dim3(S / 64, H), 256, 0, stream>>>(qkv, Vt);
        k_attn_mfma<<<dim3(S / 64, H), 256, 0, stream>>>(Qh, Kh, Vt, slopes, ao_bf);
        k_gemm_bf<true><<<dim3(D / 128, S / 128), 256, 0, stream>>>(ao_bf, outW_bf + (long)l * D * D, x, D, D, ls1 + l * D);

        // ---- FFN block ----
        k_ln_bf<<<S, 256, 0, stream>>>(x, ln2_g + l * D, ln2_b + l * D, h_bf);
        k_gemm_bf<false><<<dim3(2 * DFF / 128, S / 128), 256, 0, stream>>>(h_bf, fc1W_bf + (long)l * 2 * DFF * D, hidden, 2 * DFF, D, nullptr);
        k_swiglu<<<S * DFF / 256, 256, 0, stream>>>(hidden, hid_bf);
        k_gemm_bf<true><<<dim3(D / 128, S / 128), 256, 0, stream>>>(hid_bf, fc2W_bf + (long)l * D * DFF, x, D, DFF, ls2 + l * D);
    }

    // ---- final LN + tied lm_head ----
    k_ln_bf<<<S, 256, 0, stream>>>(x, lnf_g, lnf_b, h_bf);
    k_gemm_bf<false><<<dim3(V / 128, S / 128), 256, 0, stream>>>(h_bf, emb_bf, (float*)d_out, V, D, nullptr);
}

// Round 5
// 1377.842 us; speedup vs baseline: 7.8829x; 1.0013x over previous
//
#include <hip/hip_runtime.h>
#include <hip/hip_bf16.h>
#include <stdint.h>

#define S 2048
#define D 768
#define H 12
#define HD 64
#define V 32000
#define R 32
#define DFF 3072
#define NLAYERS 4
#define EPS 1e-6f

typedef __bf16 bf16;
typedef __bf16 bf16x4 __attribute__((ext_vector_type(4)));
typedef __bf16 bf16x8 __attribute__((ext_vector_type(8)));
typedef float f32x4 __attribute__((ext_vector_type(4)));

// M is always S=2048 -> 16 M-tiles of 128. 1D grid, XCD-bijective swizzle,
// M-fastest so 16 consecutive logical blocks share one B-panel (L2 reuse).
__device__ __forceinline__ int swz_logical(int nwg) {
    int id = blockIdx.x;
    int q = nwg >> 3;                 // nwg % 8 == 0 for all our grids
    return (id & 7) * q + (id >> 3);
}

// ---------------- fp32 -> bf16 conversion (4 elems/thread) ----------------
__global__ __launch_bounds__(256) void k_cvt(const float* __restrict__ in,
                                             bf16* __restrict__ out, long n) {
    long i = ((long)blockIdx.x * 256 + threadIdx.x) * 4;
    if (i >= n) return;
    float4 v = *(const float4*)(in + i);
    bf16x4 o;
    o.x = (bf16)v.x; o.y = (bf16)v.y; o.z = (bf16)v.z; o.w = (bf16)v.w;
    *(bf16x4*)(out + i) = o;
}

// ---------------- A transpose: A[l][K][R] -> At[l][R][K] ----------------
__global__ __launch_bounds__(256) void k_atrans(const float* __restrict__ A,
                                                float* __restrict__ At, int K) {
    int idx = blockIdx.x * 256 + threadIdx.x;
    int l = idx / (R * K);
    int j = idx % (R * K);
    int r = j / K, k = j % K;
    At[idx] = A[(long)l * K * R + (long)k * R + r];
}

// ---- LoRA fold: Wb[n,k] = bf16( W[n,k] + (1/R) * sum_r At[r,k]*B[r,n] ) ----
__global__ __launch_bounds__(256) void k_fold(const float* __restrict__ W,
                                              const float* __restrict__ At,
                                              const float* __restrict__ B,
                                              bf16* __restrict__ Wb,
                                              int N, int K) {
    int l = blockIdx.z;
    const float* Wl  = W  + (long)l * N * K;
    const float* Atl = At + (long)l * R * K;
    const float* Bl  = B  + (long)l * R * N;
    bf16* Wbl = Wb + (long)l * N * K;
    int k = blockIdx.x * 256 + threadIdx.x;
    int n0 = blockIdx.y * 8;
    float acc[8];
    #pragma unroll
    for (int j = 0; j < 8; ++j) acc[j] = Wl[(long)(n0 + j) * K + k];
    for (int r = 0; r < R; ++r) {
        float a = Atl[(long)r * K + k] * (1.0f / R);
        #pragma unroll
        for (int j = 0; j < 8; ++j)
            acc[j] = fmaf(a, Bl[(long)r * N + n0 + j], acc[j]);
    }
    #pragma unroll
    for (int j = 0; j < 8; ++j) Wbl[(long)(n0 + j) * K + k] = (bf16)acc[j];
}

// ---------------- embedding gather ----------------
__global__ void k_embed(const int* __restrict__ ids, const float* __restrict__ emb,
                        float* __restrict__ x) {
    int s = blockIdx.x;
    int row = ids[s];
    for (int d = threadIdx.x; d < D; d += blockDim.x)
        x[s * D + d] = emb[row * D + d];
}

// ---------------- layernorm -> bf16 out ----------------
__global__ __launch_bounds__(256) void k_ln_bf(const float* __restrict__ x,
                                               const float* __restrict__ g,
                                               const float* __restrict__ b,
                                               bf16* __restrict__ out) {
    int s = blockIdx.x;
    int t = threadIdx.x;
    const float* xr = x + s * D;
    float e0 = xr[t], e1 = xr[t + 256], e2 = xr[t + 512];
    float sum = e0 + e1 + e2;
    float sq = e0 * e0 + e1 * e1 + e2 * e2;
    #pragma unroll
    for (int m = 1; m < 64; m <<= 1) {
        sum += __shfl_xor(sum, m);
        sq  += __shfl_xor(sq, m);
    }
    __shared__ float ssum[4], ssq[4];
    int w = t >> 6;
    if ((t & 63) == 0) { ssum[w] = sum; ssq[w] = sq; }
    __syncthreads();
    sum = ssum[0] + ssum[1] + ssum[2] + ssum[3];
    sq  = ssq[0] + ssq[1] + ssq[2] + ssq[3];
    float mean = sum * (1.0f / D);
    float var  = sq * (1.0f / D) - mean * mean;
    float rs = rsqrtf(var + EPS);
    bf16* orow = out + (long)s * D;
    orow[t]       = (bf16)((e0 - mean) * rs * g[t]       + b[t]);
    orow[t + 256] = (bf16)((e1 - mean) * rs * g[t + 256] + b[t + 256]);
    orow[t + 512] = (bf16)((e2 - mean) * rs * g[t + 512] + b[t + 512]);
}

// ---------------- shared GEMM machinery ----------------
__device__ __forceinline__ void gload16(const bf16* g, bf16* l) {
    __builtin_amdgcn_global_load_lds(
        (const __attribute__((address_space(1))) void*)g,
        (__attribute__((address_space(3))) void*)l, 16, 0, 0);
}

// generic: C[M,N] = X[M,K] @ W[N,K]^T ; RESID: C += ls[n]*acc (in place)
template <bool RESID>
__global__ __launch_bounds__(256) void k_gemm_bf(const bf16* __restrict__ X,
                                                 const bf16* __restrict__ W,
                                                 float* __restrict__ C,
                                                 int N, int K,
                                                 const float* __restrict__ ls,
                                                 int nwg) {
    __shared__ bf16 At[128 * 32];
    __shared__ bf16 Bt[128 * 32];
    int tid = threadIdx.x;
    int w = tid >> 6, lane = tid & 63;
    int logical = swz_logical(nwg);
    long m0 = (long)(logical & 15) * 128;
    long n0 = (long)(logical >> 4) * 128;
    int wr = (w >> 1) * 64, wc = (w & 1) * 64;
    int c0 = w, c1 = w + 4;
    int rA0 = c0 * 16 + (lane >> 2);
    int rA1 = c1 * 16 + (lane >> 2);
    int ck = (lane & 3) * 8;
    int fr = lane & 15;
    int fo = (lane >> 4) * 8;
    f32x4 acc[4][4] = {};
    for (int k0 = 0; k0 < K; k0 += 32) {
        gload16(X + (m0 + rA0) * K + k0 + ck, At + c0 * 512);
        gload16(X + (m0 + rA1) * K + k0 + ck, At + c1 * 512);
        gload16(W + (n0 + rA0) * K + k0 + ck, Bt + c0 * 512);
        gload16(W + (n0 + rA1) * K + k0 + ck, Bt + c1 * 512);
        __syncthreads();
        bf16x8 a[4], b[4];
        #pragma unroll
        for (int m = 0; m < 4; m++)
            a[m] = *(const bf16x8*)(At + (wr + m * 16 + fr) * 32 + fo);
        #pragma unroll
        for (int n = 0; n < 4; n++)
            b[n] = *(const bf16x8*)(Bt + (wc + n * 16 + fr) * 32 + fo);
        #pragma unroll
        for (int m = 0; m < 4; m++)
            #pragma unroll
            for (int n = 0; n < 4; n++)
                acc[m][n] = __builtin_amdgcn_mfma_f32_16x16x32_bf16(a[m], b[n], acc[m][n], 0, 0, 0);
        __syncthreads();
    }
    int cr = (lane >> 4) * 4, cc = lane & 15;
    #pragma unroll
    for (int m = 0; m < 4; m++)
        #pragma unroll
        for (int n = 0; n < 4; n++) {
            long col = n0 + wc + n * 16 + cc;
            #pragma unroll
            for (int r = 0; r < 4; r++) {
                long idx = (m0 + wr + m * 16 + cr + r) * N + col;
                if (RESID)
                    C[idx] = fmaf(ls[col], acc[m][n][r], C[idx]);
                else
                    C[idx] = acc[m][n][r];
            }
        }
}

// qkv GEMM with fused split: cols [0,768)->Qh (x0.125), [768,1536)->Kh,
// [1536,2304)->Vt transposed ([col][s], bf16x4 along s).
__global__ __launch_bounds__(256) void k_gemm_qkv(const bf16* __restrict__ X,
                                                  const bf16* __restrict__ W,
                                                  bf16* __restrict__ Qh,
                                                  bf16* __restrict__ Kh,
                                                  bf16* __restrict__ Vt,
                                                  int nwg) {
    const int N = 3 * D, K = D;
    __shared__ bf16 At[128 * 32];
    __shared__ bf16 Bt[128 * 32];
    int tid = threadIdx.x;
    int w = tid >> 6, lane = tid & 63;
    int logical = swz_logical(nwg);
    long m0 = (long)(logical & 15) * 128;
    long n0 = (long)(logical >> 4) * 128;
    int wr = (w >> 1) * 64, wc = (w & 1) * 64;
    int c0 = w, c1 = w + 4;
    int rA0 = c0 * 16 + (lane >> 2);
    int rA1 = c1 * 16 + (lane >> 2);
    int ck = (lane & 3) * 8;
    int fr = lane & 15;
    int fo = (lane >> 4) * 8;
    f32x4 acc[4][4] = {};
    for (int k0 = 0; k0 < K; k0 += 32) {
        gload16(X + (m0 + rA0) * K + k0 + ck, At + c0 * 512);
        gload16(X + (m0 + rA1) * K + k0 + ck, At + c1 * 512);
        gload16(W + (n0 + rA0) * K + k0 + ck, Bt + c0 * 512);
        gload16(W + (n0 + rA1) * K + k0 + ck, Bt + c1 * 512);
        __syncthreads();
        bf16x8 a[4], b[4];
        #pragma unroll
        for (int m = 0; m < 4; m++)
            a[m] = *(const bf16x8*)(At + (wr + m * 16 + fr) * 32 + fo);
        #pragma unroll
        for (int n = 0; n < 4; n++)
            b[n] = *(const bf16x8*)(Bt + (wc + n * 16 + fr) * 32 + fo);
        #pragma unroll
        for (int m = 0; m < 4; m++)
            #pragma unroll
            for (int n = 0; n < 4; n++)
                acc[m][n] = __builtin_amdgcn_mfma_f32_16x16x32_bf16(a[m], b[n], acc[m][n], 0, 0, 0);
        __syncthreads();
    }
    int cr = (lane >> 4) * 4, cc = lane & 15;
    if (n0 < 1536) {
        bf16* dst = (n0 < 768) ? Qh : Kh;
        float scale = (n0 < 768) ? 0.125f : 1.0f;
        int base = (n0 < 768) ? (int)n0 : (int)n0 - 768;
        #pragma unroll
        for (int m = 0; m < 4; m++)
            #pragma unroll
            for (int n = 0; n < 4; n++) {
                int col = base + wc + n * 16 + cc;
                int h = col >> 6, d = col & 63;
                #pragma unroll
                for (int r = 0; r < 4; r++) {
                    long s = m0 + wr + m * 16 + cr + r;
                    dst[((long)h * S + s) * HD + d] = (bf16)(acc[m][n][r] * scale);
                }
            }
    } else {
        int base = (int)n0 - 1536;
        #pragma unroll
        for (int m = 0; m < 4; m++)
            #pragma unroll
            for (int n = 0; n < 4; n++) {
                int col = base + wc + n * 16 + cc;   // == h*64 + d
                long s0 = m0 + wr + m * 16 + cr;
                bf16x4 ob;
                #pragma unroll
                for (int r = 0; r < 4; r++) ob[r] = (bf16)acc[m][n][r];
                *(bf16x4*)(Vt + (long)col * S + s0) = ob;
            }
    }
}

// fc1 GEMM with fused SwiGLU: block computes gate panel (W rows f0+r) and
// act panel (W rows DFF+f0+r); writes hid_bf[s][f] = silu(g)*a.
__global__ __launch_bounds__(256) void k_gemm_fc1(const bf16* __restrict__ X,
                                                  const bf16* __restrict__ W,
                                                  bf16* __restrict__ hb,
                                                  int nwg) {
    const int K = D;
    __shared__ bf16 At[128 * 32];
    __shared__ bf16 Bg[128 * 32];
    __shared__ bf16 Ba[128 * 32];
    int tid = threadIdx.x;
    int w = tid >> 6, lane = tid & 63;
    int logical = swz_logical(nwg);
    long m0 = (long)(logical & 15) * 128;
    long f0 = (long)(logical >> 4) * 128;
    int wr = (w >> 1) * 64, wc = (w & 1) * 64;
    int c0 = w, c1 = w + 4;
    int rA0 = c0 * 16 + (lane >> 2);
    int rA1 = c1 * 16 + (lane >> 2);
    int ck = (lane & 3) * 8;
    int fr = lane & 15;
    int fo = (lane >> 4) * 8;
    const bf16* Wg = W + f0 * K;
    const bf16* Wa = W + ((long)DFF + f0) * K;
    f32x4 accG[4][4] = {}, accA[4][4] = {};
    for (int k0 = 0; k0 < K; k0 += 32) {
        gload16(X + (m0 + rA0) * K + k0 + ck, At + c0 * 512);
        gload16(X + (m0 + rA1) * K + k0 + ck, At + c1 * 512);
        gload16(Wg + (long)rA0 * K + k0 + ck, Bg + c0 * 512);
        gload16(Wg + (long)rA1 * K + k0 + ck, Bg + c1 * 512);
        gload16(Wa + (long)rA0 * K + k0 + ck, Ba + c0 * 512);
        gload16(Wa + (long)rA1 * K + k0 + ck, Ba + c1 * 512);
        __syncthreads();
        bf16x8 a[4], bg[4], ba[4];
        #pragma unroll
        for (int m = 0; m < 4; m++)
            a[m] = *(const bf16x8*)(At + (wr + m * 16 + fr) * 32 + fo);
        #pragma unroll
        for (int n = 0; n < 4; n++) {
            bg[n] = *(const bf16x8*)(Bg + (wc + n * 16 + fr) * 32 + fo);
            ba[n] = *(const bf16x8*)(Ba + (wc + n * 16 + fr) * 32 + fo);
        }
        #pragma unroll
        for (int m = 0; m < 4; m++)
            #pragma unroll
            for (int n = 0; n < 4; n++) {
                accG[m][n] = __builtin_amdgcn_mfma_f32_16x16x32_bf16(a[m], bg[n], accG[m][n], 0, 0, 0);
                accA[m][n] = __builtin_amdgcn_mfma_f32_16x16x32_bf16(a[m], ba[n], accA[m][n], 0, 0, 0);
            }
        __syncthreads();
    }
    int cr = (lane >> 4) * 4, cc = lane & 15;
    #pragma unroll
    for (int m = 0; m < 4; m++)
        #pragma unroll
        for (int n = 0; n < 4; n++) {
            long col = f0 + wc + n * 16 + cc;
            #pragma unroll
            for (int r = 0; r < 4; r++) {
                long s = m0 + wr + m * 16 + cr + r;
                float gv = accG[m][n][r], av = accA[m][n][r];
                float sig = 1.0f / (1.0f + __expf(-gv));
                hb[s * DFF + col] = (bf16)(gv * sig * av);
            }
        }
}

// ---------------- flash attention, MFMA, ALiBi+causal ----------------
__global__ __launch_bounds__(256) void k_attn_mfma(const bf16* __restrict__ Qh,
                                                   const bf16* __restrict__ Kh,
                                                   const bf16* __restrict__ Vt,
                                                   const float* __restrict__ slopes,
                                                   bf16* __restrict__ ao) {
    __shared__ bf16 Kl[64 * 64];
    __shared__ bf16 Vl[64 * 64];
    __shared__ bf16 Pl[4][16 * 72];
    int tid = threadIdx.x;
    int w = tid >> 6, lane = tid & 63;
    int fr = lane & 15, g = lane >> 4;
    int qb = gridDim.x - 1 - blockIdx.x;
    int q0 = qb * 64;
    int h = blockIdx.y;
    int ntiles = qb + 1;
    float slope = slopes[h];

    const bf16* qrow = Qh + ((long)h * S + q0 + w * 16 + fr) * HD;
    bf16x8 qf0 = *(const bf16x8*)(qrow + g * 8);
    bf16x8 qf1 = *(const bf16x8*)(qrow + 32 + g * 8);

    int ci0 = tid, ci1 = tid + 256;
    int r0 = ci0 >> 3, c0s = (ci0 & 7) ^ (r0 & 7);
    int r1 = ci1 >> 3, c1s = (ci1 & 7) ^ (r1 & 7);
    const bf16* Kg = Kh + (long)h * S * HD;
    const bf16* Vg = Vt + (long)h * HD * S;

    float m = -1e9f, l = 0.f;
    f32x4 o[4] = {};
    int qg = q0 + w * 16 + fr;

    for (int t = 0; t < ntiles; ++t) {
        int j0 = t * 64;
        __syncthreads();
        gload16(Kg + (long)(j0 + r0) * HD + c0s * 8, Kl + ci0 * 8);
        gload16(Kg + (long)(j0 + r1) * HD + c1s * 8, Kl + ci1 * 8);
        gload16(Vg + (long)r0 * S + j0 + c0s * 8, Vl + ci0 * 8);
        gload16(Vg + (long)r1 * S + j0 + c1s * 8, Vl + ci1 * 8);
        __syncthreads();

        f32x4 sc[4];
        #pragma unroll
        for (int jt = 0; jt < 4; ++jt) {
            int jr = jt * 16 + fr;
            bf16x8 kf0 = *(const bf16x8*)(Kl + jr * 64 + ((g ^ (jr & 7)) * 8));
            bf16x8 kf1 = *(const bf16x8*)(Kl + jr * 64 + (((g + 4) ^ (jr & 7)) * 8));
            f32x4 z = {};
            z = __builtin_amdgcn_mfma_f32_16x16x32_bf16(kf0, qf0, z, 0, 0, 0);
            z = __builtin_amdgcn_mfma_f32_16x16x32_bf16(kf1, qf1, z, 0, 0, 0);
            sc[jt] = z;
        }
        float s[4][4];
        float mt = -1e9f;
        #pragma unroll
        for (int jt = 0; jt < 4; ++jt)
            #pragma unroll
            for (int r = 0; r < 4; ++r) {
                int jg = j0 + jt * 16 + g * 4 + r;
                int rel = jg - qg;
                float v = (rel <= 0) ? fmaf(slope, (float)rel, sc[jt][r]) : -1e9f;
                s[jt][r] = v;
                mt = fmaxf(mt, v);
            }
        mt = fmaxf(mt, __shfl_xor(mt, 16));
        mt = fmaxf(mt, __shfl_xor(mt, 32));
        float mnew = fmaxf(m, mt);
        float factor = __expf(m - mnew);
        float psum = 0.f;
        #pragma unroll
        for (int jt = 0; jt < 4; ++jt) {
            bf16x4 pb;
            #pragma unroll
            for (int r = 0; r < 4; ++r) {
                float p = __expf(s[jt][r] - mnew);
                psum += p;
                pb[r] = (bf16)p;
            }
            *(bf16x4*)(&Pl[w][fr * 72 + jt * 16 + g * 4]) = pb;
        }
        psum += __shfl_xor(psum, 16);
        psum += __shfl_xor(psum, 32);
        l = l * factor + psum;
        m = mnew;
        #pragma unroll
        for (int dt = 0; dt < 4; ++dt)
            #pragma unroll
            for (int r = 0; r < 4; ++r) o[dt][r] *= factor;

        bf16x8 pf0 = *(const bf16x8*)(&Pl[w][fr * 72 + g * 8]);
        bf16x8 pf1 = *(const bf16x8*)(&Pl[w][fr * 72 + 32 + g * 8]);
        #pragma unroll
        for (int dt = 0; dt < 4; ++dt) {
            int dr = dt * 16 + fr;
            bf16x8 vf0 = *(const bf16x8*)(Vl + dr * 64 + ((g ^ (dr & 7)) * 8));
            bf16x8 vf1 = *(const bf16x8*)(Vl + dr * 64 + (((g + 4) ^ (dr & 7)) * 8));
            o[dt] = __builtin_amdgcn_mfma_f32_16x16x32_bf16(vf0, pf0, o[dt], 0, 0, 0);
            o[dt] = __builtin_amdgcn_mfma_f32_16x16x32_bf16(vf1, pf1, o[dt], 0, 0, 0);
        }
    }
    float inv = 1.0f / l;
    bf16* orow = ao + ((long)(q0 + w * 16 + fr)) * D + h * HD;
    #pragma unroll
    for (int dt = 0; dt < 4; ++dt) {
        bf16x4 ob;
        #pragma unroll
        for (int r = 0; r < 4; ++r) ob[r] = (bf16)(o[dt][r] * inv);
        *(bf16x4*)(orow + dt * 16 + g * 4) = ob;
    }
}

extern "C" void kernel_launch(void* const* d_in, const int* in_sizes, int n_in,
                              void* d_out, int out_size, void* d_ws, size_t ws_size,
                              hipStream_t stream) {
    const int*   ids    = (const int*)d_in[0];
    const float* emb    = (const float*)d_in[1];
    const float* slopes = (const float*)d_in[2];
    const float* ln1_g  = (const float*)d_in[3];
    const float* ln1_b  = (const float*)d_in[4];
    const float* qkv_W  = (const float*)d_in[5];
    const float* qkv_A  = (const float*)d_in[6];
    const float* qkv_B  = (const float*)d_in[7];
    const float* out_W  = (const float*)d_in[8];
    const float* out_A  = (const float*)d_in[9];
    const float* out_B  = (const float*)d_in[10];
    const float* ln2_g  = (const float*)d_in[11];
    const float* ln2_b  = (const float*)d_in[12];
    const float* fc1_W  = (const float*)d_in[13];
    const float* fc1_A  = (const float*)d_in[14];
    const float* fc1_B  = (const float*)d_in[15];
    const float* fc2_W  = (const float*)d_in[16];
    const float* fc2_A  = (const float*)d_in[17];
    const float* fc2_B  = (const float*)d_in[18];
    const float* ls1    = (const float*)d_in[19];
    const float* ls2    = (const float*)d_in[20];
    const float* lnf_g  = (const float*)d_in[21];
    const float* lnf_b  = (const float*)d_in[22];

    // ---- workspace layout ----
    char* p = (char*)d_ws;
    float* x      = (float*)p;               p += (long)S * D * 4;
    bf16* h_bf    = (bf16*)p;                p += (long)S * D * 2;
    bf16* ao_bf   = (bf16*)p;                p += (long)S * D * 2;
    bf16* hid_bf  = (bf16*)p;                p += (long)S * DFF * 2;
    bf16* Qh      = (bf16*)p;                p += (long)H * S * HD * 2;
    bf16* Kh      = (bf16*)p;                p += (long)H * S * HD * 2;
    bf16* Vt      = (bf16*)p;                p += (long)H * HD * S * 2;
    bf16* emb_bf  = (bf16*)p;                p += (long)V * D * 2;
    bf16* qkvW_bf = (bf16*)p;                p += (long)NLAYERS * 3 * D * D * 2;
    bf16* outW_bf = (bf16*)p;                p += (long)NLAYERS * D * D * 2;
    bf16* fc1W_bf = (bf16*)p;                p += (long)NLAYERS * 2 * DFF * D * 2;
    bf16* fc2W_bf = (bf16*)p;                p += (long)NLAYERS * D * DFF * 2;
    float* qkvA_t = (float*)p;               p += (long)NLAYERS * R * D * 4;
    float* outA_t = (float*)p;               p += (long)NLAYERS * R * D * 4;
    float* fc1A_t = (float*)p;               p += (long)NLAYERS * R * D * 4;
    float* fc2A_t = (float*)p;               p += (long)NLAYERS * R * DFF * 4;

    // ---- weight prep ----
    k_atrans<<<NLAYERS * R * D / 256, 256, 0, stream>>>(qkv_A, qkvA_t, D);
    k_atrans<<<NLAYERS * R * D / 256, 256, 0, stream>>>(out_A, outA_t, D);
    k_atrans<<<NLAYERS * R * D / 256, 256, 0, stream>>>(fc1_A, fc1A_t, D);
    k_atrans<<<NLAYERS * R * DFF / 256, 256, 0, stream>>>(fc2_A, fc2A_t, DFF);
    k_fold<<<dim3(D / 256, 3 * D / 8, NLAYERS), 256, 0, stream>>>(qkv_W, qkvA_t, qkv_B, qkvW_bf, 3 * D, D);
    k_fold<<<dim3(D / 256, D / 8, NLAYERS), 256, 0, stream>>>(out_W, outA_t, out_B, outW_bf, D, D);
    k_fold<<<dim3(D / 256, 2 * DFF / 8, NLAYERS), 256, 0, stream>>>(fc1_W, fc1A_t, fc1_B, fc1W_bf, 2 * DFF, D);
    k_fold<<<dim3(DFF / 256, D / 8, NLAYERS), 256, 0, stream>>>(fc2_W, fc2A_t, fc2_B, fc2W_bf, D, DFF);
    {
        long n = (long)V * D;
        k_cvt<<<(n / 4 + 255) / 256, 256, 0, stream>>>(emb, emb_bf, n);
    }

    k_embed<<<S, 256, 0, stream>>>(ids, emb, x);

    const int NWG_QKV = (3 * D / 128) * 16;   // 288
    const int NWG_OUT = (D / 128) * 16;       // 96
    const int NWG_FC1 = (DFF / 128) * 16;     // 384
    const int NWG_FC2 = (D / 128) * 16;       // 96
    const int NWG_LM  = (V / 128) * 16;       // 4000

    for (int l = 0; l < NLAYERS; l++) {
        // ---- attention block ----
        k_ln_bf<<<S, 256, 0, stream>>>(x, ln1_g + l * D, ln1_b + l * D, h_bf);
        k_gemm_qkv<<<NWG_QKV, 256, 0, stream>>>(h_bf, qkvW_bf + (long)l * 3 * D * D, Qh, Kh, Vt, NWG_QKV);
        k_attn_mfma<<<dim3(S / 64, H), 256, 0, stream>>>(Qh, Kh, Vt, slopes, ao_bf);
        k_gemm_bf<true><<<NWG_OUT, 256, 0, stream>>>(ao_bf, outW_bf + (long)l * D * D, x, D, D, ls1 + l * D, NWG_OUT);

        // ---- FFN block ----
        k_ln_bf<<<S, 256, 0, stream>>>(x, ln2_g + l * D, ln2_b + l * D, h_bf);
        k_gemm_fc1<<<NWG_FC1, 256, 0, stream>>>(h_bf, fc1W_bf + (long)l * 2 * DFF * D, hid_bf, NWG_FC1);
        k_gemm_bf<true><<<NWG_FC2, 256, 0, stream>>>(hid_bf, fc2W_bf + (long)l * D * DFF, x, D, DFF, ls2 + l * D, NWG_FC2);
    }

    // ---- final LN + tied lm_head ----
    k_ln_bf<<<S, 256, 0, stream>>>(x, lnf_g, lnf_b, h_bf);
    k_gemm_bf<false><<<NWG_LM, 256, 0, stream>>>(h_bf, emb_bf, (float*)d_out, V, D, nullptr, NWG_LM);
}

// Round 6
// 1322.540 us; speedup vs baseline: 8.2125x; 1.0418x over previous
//
#include <hip/hip_runtime.h>
#include <hip/hip_bf16.h>
#include <stdint.h>

#define S 2048
#define D 768
#define H 12
#define HD 64
#define V 32000
#define R 32
#define DFF 3072
#define NLAYERS 4
#define EPS 1e-6f

typedef __bf16 bf16;
typedef __bf16 bf16x4 __attribute__((ext_vector_type(4)));
typedef __bf16 bf16x8 __attribute__((ext_vector_type(8)));
typedef float f32x4 __attribute__((ext_vector_type(4)));

// 1D grid, XCD-bijective swizzle (nwg % 8 == 0 for all grids), M-fastest so
// consecutive logical blocks share one B-panel (L2 reuse).
__device__ __forceinline__ int swz_logical(int nwg) {
    int id = blockIdx.x;
    int q = nwg >> 3;
    return (id & 7) * q + (id >> 3);
}

// ---------------- fp32 -> bf16 conversion ----------------
__global__ __launch_bounds__(256) void k_cvt(const float* __restrict__ in,
                                             bf16* __restrict__ out, long n) {
    long i = ((long)blockIdx.x * 256 + threadIdx.x) * 4;
    if (i >= n) return;
    float4 v = *(const float4*)(in + i);
    bf16x4 o;
    o.x = (bf16)v.x; o.y = (bf16)v.y; o.z = (bf16)v.z; o.w = (bf16)v.w;
    *(bf16x4*)(out + i) = o;
}

// ---- LoRA fold (A read directly, staged in LDS): ----
// Wb[n,k] = bf16( W[n,k] + (1/R) * sum_r A[k,r]*B[r,n] )
__global__ __launch_bounds__(256) void k_fold(const float* __restrict__ W,
                                              const float* __restrict__ A,
                                              const float* __restrict__ B,
                                              bf16* __restrict__ Wb,
                                              int N, int K) {
    __shared__ float As[256][33];   // [k_local][r], +1 pad
    int l = blockIdx.z;
    const float* Wl = W + (long)l * N * K;
    const float* Al = A + (long)l * K * R;
    const float* Bl = B + (long)l * R * N;
    bf16* Wbl = Wb + (long)l * N * K;
    int t = threadIdx.x;
    long k0 = (long)blockIdx.x * 256;
    int n0 = blockIdx.y * 8;
    const float* Ab = Al + k0 * R;      // contiguous 256*32 floats
    #pragma unroll
    for (int i = 0; i < 32; ++i) {
        int idx = i * 256 + t;
        As[idx >> 5][idx & 31] = Ab[idx];
    }
    __syncthreads();
    long k = k0 + t;
    float acc[8];
    #pragma unroll
    for (int j = 0; j < 8; ++j) acc[j] = Wl[(long)(n0 + j) * K + k];
    for (int r = 0; r < R; ++r) {
        float a = As[t][r] * (1.0f / R);
        #pragma unroll
        for (int j = 0; j < 8; ++j)
            acc[j] = fmaf(a, Bl[(long)r * N + n0 + j], acc[j]);
    }
    #pragma unroll
    for (int j = 0; j < 8; ++j) Wbl[(long)(n0 + j) * K + k] = (bf16)acc[j];
}

// ---------------- embedding gather ----------------
__global__ void k_embed(const int* __restrict__ ids, const float* __restrict__ emb,
                        float* __restrict__ x) {
    int s = blockIdx.x;
    int row = ids[s];
    for (int d = threadIdx.x; d < D; d += blockDim.x)
        x[s * D + d] = emb[row * D + d];
}

// ---------------- layernorm -> bf16 out ----------------
__global__ __launch_bounds__(256) void k_ln_bf(const float* __restrict__ x,
                                               const float* __restrict__ g,
                                               const float* __restrict__ b,
                                               bf16* __restrict__ out) {
    int s = blockIdx.x;
    int t = threadIdx.x;
    const float* xr = x + s * D;
    float e0 = xr[t], e1 = xr[t + 256], e2 = xr[t + 512];
    float sum = e0 + e1 + e2;
    float sq = e0 * e0 + e1 * e1 + e2 * e2;
    #pragma unroll
    for (int m = 1; m < 64; m <<= 1) {
        sum += __shfl_xor(sum, m);
        sq  += __shfl_xor(sq, m);
    }
    __shared__ float ssum[4], ssq[4];
    int w = t >> 6;
    if ((t & 63) == 0) { ssum[w] = sum; ssq[w] = sq; }
    __syncthreads();
    sum = ssum[0] + ssum[1] + ssum[2] + ssum[3];
    sq  = ssq[0] + ssq[1] + ssq[2] + ssq[3];
    float mean = sum * (1.0f / D);
    float var  = sq * (1.0f / D) - mean * mean;
    float rs = rsqrtf(var + EPS);
    bf16* orow = out + (long)s * D;
    orow[t]       = (bf16)((e0 - mean) * rs * g[t]       + b[t]);
    orow[t + 256] = (bf16)((e1 - mean) * rs * g[t + 256] + b[t + 256]);
    orow[t + 512] = (bf16)((e2 - mean) * rs * g[t + 512] + b[t + 512]);
}

// ---------------- shared GEMM machinery ----------------
__device__ __forceinline__ void gload16(const bf16* g, bf16* l) {
    __builtin_amdgcn_global_load_lds(
        (const __attribute__((address_space(1))) void*)g,
        (__attribute__((address_space(3))) void*)l, 16, 0, 0);
}

// 128x128 tile: C[M,N(stride)] = X[M,K] @ W[N,K]^T ; col offset ncol0 for
// split-N dispatch. RESID: C += ls[col]*acc in place. TAG: distinct symbols.
template <bool RESID, int TAG>
__global__ __launch_bounds__(256) void k_gemm_bf(const bf16* __restrict__ X,
                                                 const bf16* __restrict__ W,
                                                 float* __restrict__ C,
                                                 int N, int K,
                                                 const float* __restrict__ ls,
                                                 int nwg, int ncol0) {
    __shared__ bf16 At[128 * 32];
    __shared__ bf16 Bt[128 * 32];
    int tid = threadIdx.x;
    int w = tid >> 6, lane = tid & 63;
    int logical = swz_logical(nwg);
    long m0 = (long)(logical & 15) * 128;
    long n0 = (long)(logical >> 4) * 128;
    int wr = (w >> 1) * 64, wc = (w & 1) * 64;
    int c0 = w, c1 = w + 4;
    int rA0 = c0 * 16 + (lane >> 2);
    int rA1 = c1 * 16 + (lane >> 2);
    int ck = (lane & 3) * 8;
    int fr = lane & 15;
    int fo = (lane >> 4) * 8;
    f32x4 acc[4][4] = {};
    for (int k0 = 0; k0 < K; k0 += 32) {
        gload16(X + (m0 + rA0) * K + k0 + ck, At + c0 * 512);
        gload16(X + (m0 + rA1) * K + k0 + ck, At + c1 * 512);
        gload16(W + (n0 + rA0) * K + k0 + ck, Bt + c0 * 512);
        gload16(W + (n0 + rA1) * K + k0 + ck, Bt + c1 * 512);
        __syncthreads();
        bf16x8 a[4], b[4];
        #pragma unroll
        for (int m = 0; m < 4; m++)
            a[m] = *(const bf16x8*)(At + (wr + m * 16 + fr) * 32 + fo);
        #pragma unroll
        for (int n = 0; n < 4; n++)
            b[n] = *(const bf16x8*)(Bt + (wc + n * 16 + fr) * 32 + fo);
        #pragma unroll
        for (int m = 0; m < 4; m++)
            #pragma unroll
            for (int n = 0; n < 4; n++)
                acc[m][n] = __builtin_amdgcn_mfma_f32_16x16x32_bf16(a[m], b[n], acc[m][n], 0, 0, 0);
        __syncthreads();
    }
    int cr = (lane >> 4) * 4, cc = lane & 15;
    #pragma unroll
    for (int m = 0; m < 4; m++)
        #pragma unroll
        for (int n = 0; n < 4; n++) {
            long col = ncol0 + n0 + wc + n * 16 + cc;
            #pragma unroll
            for (int r = 0; r < 4; r++) {
                long idx = (m0 + wr + m * 16 + cr + r) * N + col;
                if (RESID)
                    C[idx] = fmaf(ls[col], acc[m][n][r], C[idx]);
                else
                    C[idx] = acc[m][n][r];
            }
        }
}

// 64x128 tile for small-N GEMMs (out-proj, fc2): 2x better CU coverage.
// C[m,n] += ls[n]*acc (always RESID). M-tiles = 32.
template <int TAG>
__global__ __launch_bounds__(256) void k_gemm_small(const bf16* __restrict__ X,
                                                    const bf16* __restrict__ W,
                                                    float* __restrict__ C,
                                                    int N, int K,
                                                    const float* __restrict__ ls,
                                                    int nwg) {
    __shared__ bf16 At[64 * 32];
    __shared__ bf16 Bt[128 * 32];
    int tid = threadIdx.x;
    int w = tid >> 6, lane = tid & 63;
    int logical = swz_logical(nwg);
    long m0 = (long)(logical & 31) * 64;
    long n0 = (long)(logical >> 5) * 128;
    int wr = (w >> 1) * 32, wc = (w & 1) * 64;
    int rA = tid >> 2;               // A chunk: 1 per thread (rows 0..63)
    int rB0 = tid >> 2, rB1 = 64 + (tid >> 2);
    int ck = (tid & 3) * 8;
    int fr = lane & 15;
    int fo = (lane >> 4) * 8;
    f32x4 acc[2][4] = {};
    for (int k0 = 0; k0 < K; k0 += 32) {
        gload16(X + (m0 + rA) * K + k0 + ck, At + tid * 8);
        gload16(W + (n0 + rB0) * K + k0 + ck, Bt + tid * 8);
        gload16(W + (n0 + rB1) * K + k0 + ck, Bt + 2048 + tid * 8);
        __syncthreads();
        bf16x8 a[2], b[4];
        #pragma unroll
        for (int m = 0; m < 2; m++)
            a[m] = *(const bf16x8*)(At + (wr + m * 16 + fr) * 32 + fo);
        #pragma unroll
        for (int n = 0; n < 4; n++)
            b[n] = *(const bf16x8*)(Bt + (wc + n * 16 + fr) * 32 + fo);
        #pragma unroll
        for (int m = 0; m < 2; m++)
            #pragma unroll
            for (int n = 0; n < 4; n++)
                acc[m][n] = __builtin_amdgcn_mfma_f32_16x16x32_bf16(a[m], b[n], acc[m][n], 0, 0, 0);
        __syncthreads();
    }
    int cr = (lane >> 4) * 4, cc = lane & 15;
    #pragma unroll
    for (int m = 0; m < 2; m++)
        #pragma unroll
        for (int n = 0; n < 4; n++) {
            long col = n0 + wc + n * 16 + cc;
            #pragma unroll
            for (int r = 0; r < 4; r++) {
                long idx = (m0 + wr + m * 16 + cr + r) * N + col;
                C[idx] = fmaf(ls[col], acc[m][n][r], C[idx]);
            }
        }
}

// qkv GEMM with fused split: cols [0,768)->Qh (x0.125), [768,1536)->Kh,
// [1536,2304)->Vt transposed ([col][s]).
__global__ __launch_bounds__(256) void k_gemm_qkv(const bf16* __restrict__ X,
                                                  const bf16* __restrict__ W,
                                                  bf16* __restrict__ Qh,
                                                  bf16* __restrict__ Kh,
                                                  bf16* __restrict__ Vt,
                                                  int nwg) {
    const int K = D;
    __shared__ bf16 At[128 * 32];
    __shared__ bf16 Bt[128 * 32];
    int tid = threadIdx.x;
    int w = tid >> 6, lane = tid & 63;
    int logical = swz_logical(nwg);
    long m0 = (long)(logical & 15) * 128;
    long n0 = (long)(logical >> 4) * 128;
    int wr = (w >> 1) * 64, wc = (w & 1) * 64;
    int c0 = w, c1 = w + 4;
    int rA0 = c0 * 16 + (lane >> 2);
    int rA1 = c1 * 16 + (lane >> 2);
    int ck = (lane & 3) * 8;
    int fr = lane & 15;
    int fo = (lane >> 4) * 8;
    f32x4 acc[4][4] = {};
    for (int k0 = 0; k0 < K; k0 += 32) {
        gload16(X + (m0 + rA0) * K + k0 + ck, At + c0 * 512);
        gload16(X + (m0 + rA1) * K + k0 + ck, At + c1 * 512);
        gload16(W + (n0 + rA0) * K + k0 + ck, Bt + c0 * 512);
        gload16(W + (n0 + rA1) * K + k0 + ck, Bt + c1 * 512);
        __syncthreads();
        bf16x8 a[4], b[4];
        #pragma unroll
        for (int m = 0; m < 4; m++)
            a[m] = *(const bf16x8*)(At + (wr + m * 16 + fr) * 32 + fo);
        #pragma unroll
        for (int n = 0; n < 4; n++)
            b[n] = *(const bf16x8*)(Bt + (wc + n * 16 + fr) * 32 + fo);
        #pragma unroll
        for (int m = 0; m < 4; m++)
            #pragma unroll
            for (int n = 0; n < 4; n++)
                acc[m][n] = __builtin_amdgcn_mfma_f32_16x16x32_bf16(a[m], b[n], acc[m][n], 0, 0, 0);
        __syncthreads();
    }
    int cr = (lane >> 4) * 4, cc = lane & 15;
    if (n0 < 1536) {
        bf16* dst = (n0 < 768) ? Qh : Kh;
        float scale = (n0 < 768) ? 0.125f : 1.0f;
        int base = (n0 < 768) ? (int)n0 : (int)n0 - 768;
        #pragma unroll
        for (int m = 0; m < 4; m++)
            #pragma unroll
            for (int n = 0; n < 4; n++) {
                int col = base + wc + n * 16 + cc;
                int h = col >> 6, d = col & 63;
                #pragma unroll
                for (int r = 0; r < 4; r++) {
                    long s = m0 + wr + m * 16 + cr + r;
                    dst[((long)h * S + s) * HD + d] = (bf16)(acc[m][n][r] * scale);
                }
            }
    } else {
        int base = (int)n0 - 1536;
        #pragma unroll
        for (int m = 0; m < 4; m++)
            #pragma unroll
            for (int n = 0; n < 4; n++) {
                int col = base + wc + n * 16 + cc;
                long s0 = m0 + wr + m * 16 + cr;
                bf16x4 ob;
                #pragma unroll
                for (int r = 0; r < 4; r++) ob[r] = (bf16)acc[m][n][r];
                *(bf16x4*)(Vt + (long)col * S + s0) = ob;
            }
    }
}

// fc1 GEMM with fused SwiGLU.
__global__ __launch_bounds__(256) void k_gemm_fc1(const bf16* __restrict__ X,
                                                  const bf16* __restrict__ W,
                                                  bf16* __restrict__ hb,
                                                  int nwg) {
    const int K = D;
    __shared__ bf16 At[128 * 32];
    __shared__ bf16 Bg[128 * 32];
    __shared__ bf16 Ba[128 * 32];
    int tid = threadIdx.x;
    int w = tid >> 6, lane = tid & 63;
    int logical = swz_logical(nwg);
    long m0 = (long)(logical & 15) * 128;
    long f0 = (long)(logical >> 4) * 128;
    int wr = (w >> 1) * 64, wc = (w & 1) * 64;
    int c0 = w, c1 = w + 4;
    int rA0 = c0 * 16 + (lane >> 2);
    int rA1 = c1 * 16 + (lane >> 2);
    int ck = (lane & 3) * 8;
    int fr = lane & 15;
    int fo = (lane >> 4) * 8;
    const bf16* Wg = W + f0 * K;
    const bf16* Wa = W + ((long)DFF + f0) * K;
    f32x4 accG[4][4] = {}, accA[4][4] = {};
    for (int k0 = 0; k0 < K; k0 += 32) {
        gload16(X + (m0 + rA0) * K + k0 + ck, At + c0 * 512);
        gload16(X + (m0 + rA1) * K + k0 + ck, At + c1 * 512);
        gload16(Wg + (long)rA0 * K + k0 + ck, Bg + c0 * 512);
        gload16(Wg + (long)rA1 * K + k0 + ck, Bg + c1 * 512);
        gload16(Wa + (long)rA0 * K + k0 + ck, Ba + c0 * 512);
        gload16(Wa + (long)rA1 * K + k0 + ck, Ba + c1 * 512);
        __syncthreads();
        bf16x8 a[4], bg[4], ba[4];
        #pragma unroll
        for (int m = 0; m < 4; m++)
            a[m] = *(const bf16x8*)(At + (wr + m * 16 + fr) * 32 + fo);
        #pragma unroll
        for (int n = 0; n < 4; n++) {
            bg[n] = *(const bf16x8*)(Bg + (wc + n * 16 + fr) * 32 + fo);
            ba[n] = *(const bf16x8*)(Ba + (wc + n * 16 + fr) * 32 + fo);
        }
        #pragma unroll
        for (int m = 0; m < 4; m++)
            #pragma unroll
            for (int n = 0; n < 4; n++) {
                accG[m][n] = __builtin_amdgcn_mfma_f32_16x16x32_bf16(a[m], bg[n], accG[m][n], 0, 0, 0);
                accA[m][n] = __builtin_amdgcn_mfma_f32_16x16x32_bf16(a[m], ba[n], accA[m][n], 0, 0, 0);
            }
        __syncthreads();
    }
    int cr = (lane >> 4) * 4, cc = lane & 15;
    #pragma unroll
    for (int m = 0; m < 4; m++)
        #pragma unroll
        for (int n = 0; n < 4; n++) {
            long col = f0 + wc + n * 16 + cc;
            #pragma unroll
            for (int r = 0; r < 4; r++) {
                long s = m0 + wr + m * 16 + cr + r;
                float gv = accG[m][n][r], av = accA[m][n][r];
                float sig = 1.0f / (1.0f + __expf(-gv));
                hb[s * DFF + col] = (bf16)(gv * sig * av);
            }
        }
}

// ---------------- flash attention, MFMA, ALiBi+causal ----------------
__global__ __launch_bounds__(256) void k_attn_mfma(const bf16* __restrict__ Qh,
                                                   const bf16* __restrict__ Kh,
                                                   const bf16* __restrict__ Vt,
                                                   const float* __restrict__ slopes,
                                                   bf16* __restrict__ ao) {
    __shared__ bf16 Kl[64 * 64];
    __shared__ bf16 Vl[64 * 64];
    __shared__ bf16 Pl[4][16 * 72];
    int tid = threadIdx.x;
    int w = tid >> 6, lane = tid & 63;
    int fr = lane & 15, g = lane >> 4;
    int qb = gridDim.x - 1 - blockIdx.x;
    int q0 = qb * 64;
    int h = blockIdx.y;
    int ntiles = qb + 1;
    float slope = slopes[h];

    const bf16* qrow = Qh + ((long)h * S + q0 + w * 16 + fr) * HD;
    bf16x8 qf0 = *(const bf16x8*)(qrow + g * 8);
    bf16x8 qf1 = *(const bf16x8*)(qrow + 32 + g * 8);

    int ci0 = tid, ci1 = tid + 256;
    int r0 = ci0 >> 3, c0s = (ci0 & 7) ^ (r0 & 7);
    int r1 = ci1 >> 3, c1s = (ci1 & 7) ^ (r1 & 7);
    const bf16* Kg = Kh + (long)h * S * HD;
    const bf16* Vg = Vt + (long)h * HD * S;

    float m = -1e9f, l = 0.f;
    f32x4 o[4] = {};
    int qg = q0 + w * 16 + fr;

    for (int t = 0; t < ntiles; ++t) {
        int j0 = t * 64;
        __syncthreads();
        gload16(Kg + (long)(j0 + r0) * HD + c0s * 8, Kl + ci0 * 8);
        gload16(Kg + (long)(j0 + r1) * HD + c1s * 8, Kl + ci1 * 8);
        gload16(Vg + (long)r0 * S + j0 + c0s * 8, Vl + ci0 * 8);
        gload16(Vg + (long)r1 * S + j0 + c1s * 8, Vl + ci1 * 8);
        __syncthreads();

        f32x4 sc[4];
        #pragma unroll
        for (int jt = 0; jt < 4; ++jt) {
            int jr = jt * 16 + fr;
            bf16x8 kf0 = *(const bf16x8*)(Kl + jr * 64 + ((g ^ (jr & 7)) * 8));
            bf16x8 kf1 = *(const bf16x8*)(Kl + jr * 64 + (((g + 4) ^ (jr & 7)) * 8));
            f32x4 z = {};
            z = __builtin_amdgcn_mfma_f32_16x16x32_bf16(kf0, qf0, z, 0, 0, 0);
            z = __builtin_amdgcn_mfma_f32_16x16x32_bf16(kf1, qf1, z, 0, 0, 0);
            sc[jt] = z;
        }
        float s[4][4];
        float mt = -1e9f;
        #pragma unroll
        for (int jt = 0; jt < 4; ++jt)
            #pragma unroll
            for (int r = 0; r < 4; ++r) {
                int jg = j0 + jt * 16 + g * 4 + r;
                int rel = jg - qg;
                float v = (rel <= 0) ? fmaf(slope, (float)rel, sc[jt][r]) : -1e9f;
                s[jt][r] = v;
                mt = fmaxf(mt, v);
            }
        mt = fmaxf(mt, __shfl_xor(mt, 16));
        mt = fmaxf(mt, __shfl_xor(mt, 32));
        float mnew = fmaxf(m, mt);
        float factor = __expf(m - mnew);
        float psum = 0.f;
        #pragma unroll
        for (int jt = 0; jt < 4; ++jt) {
            bf16x4 pb;
            #pragma unroll
            for (int r = 0; r < 4; ++r) {
                float p = __expf(s[jt][r] - mnew);
                psum += p;
                pb[r] = (bf16)p;
            }
            *(bf16x4*)(&Pl[w][fr * 72 + jt * 16 + g * 4]) = pb;
        }
        psum += __shfl_xor(psum, 16);
        psum += __shfl_xor(psum, 32);
        l = l * factor + psum;
        m = mnew;
        #pragma unroll
        for (int dt = 0; dt < 4; ++dt)
            #pragma unroll
            for (int r = 0; r < 4; ++r) o[dt][r] *= factor;

        bf16x8 pf0 = *(const bf16x8*)(&Pl[w][fr * 72 + g * 8]);
        bf16x8 pf1 = *(const bf16x8*)(&Pl[w][fr * 72 + 32 + g * 8]);
        #pragma unroll
        for (int dt = 0; dt < 4; ++dt) {
            int dr = dt * 16 + fr;
            bf16x8 vf0 = *(const bf16x8*)(Vl + dr * 64 + ((g ^ (dr & 7)) * 8));
            bf16x8 vf1 = *(const bf16x8*)(Vl + dr * 64 + (((g + 4) ^ (dr & 7)) * 8));
            o[dt] = __builtin_amdgcn_mfma_f32_16x16x32_bf16(vf0, pf0, o[dt], 0, 0, 0);
            o[dt] = __builtin_amdgcn_mfma_f32_16x16x32_bf16(vf1, pf1, o[dt], 0, 0, 0);
        }
    }
    float inv = 1.0f / l;
    bf16* orow = ao + ((long)(q0 + w * 16 + fr)) * D + h * HD;
    #pragma unroll
    for (int dt = 0; dt < 4; ++dt) {
        bf16x4 ob;
        #pragma unroll
        for (int r = 0; r < 4; ++r) ob[r] = (bf16)(o[dt][r] * inv);
        *(bf16x4*)(orow + dt * 16 + g * 4) = ob;
    }
}

extern "C" void kernel_launch(void* const* d_in, const int* in_sizes, int n_in,
                              void* d_out, int out_size, void* d_ws, size_t ws_size,
                              hipStream_t stream) {
    const int*   ids    = (const int*)d_in[0];
    const float* emb    = (const float*)d_in[1];
    const float* slopes = (const float*)d_in[2];
    const float* ln1_g  = (const float*)d_in[3];
    const float* ln1_b  = (const float*)d_in[4];
    const float* qkv_W  = (const float*)d_in[5];
    const float* qkv_A  = (const float*)d_in[6];
    const float* qkv_B  = (const float*)d_in[7];
    const float* out_W  = (const float*)d_in[8];
    const float* out_A  = (const float*)d_in[9];
    const float* out_B  = (const float*)d_in[10];
    const float* ln2_g  = (const float*)d_in[11];
    const float* ln2_b  = (const float*)d_in[12];
    const float* fc1_W  = (const float*)d_in[13];
    const float* fc1_A  = (const float*)d_in[14];
    const float* fc1_B  = (const float*)d_in[15];
    const float* fc2_W  = (const float*)d_in[16];
    const float* fc2_A  = (const float*)d_in[17];
    const float* fc2_B  = (const float*)d_in[18];
    const float* ls1    = (const float*)d_in[19];
    const float* ls2    = (const float*)d_in[20];
    const float* lnf_g  = (const float*)d_in[21];
    const float* lnf_b  = (const float*)d_in[22];

    // ---- workspace layout ----
    char* p = (char*)d_ws;
    float* x      = (float*)p;               p += (long)S * D * 4;
    bf16* h_bf    = (bf16*)p;                p += (long)S * D * 2;
    bf16* ao_bf   = (bf16*)p;                p += (long)S * D * 2;
    bf16* hid_bf  = (bf16*)p;                p += (long)S * DFF * 2;
    bf16* Qh      = (bf16*)p;                p += (long)H * S * HD * 2;
    bf16* Kh      = (bf16*)p;                p += (long)H * S * HD * 2;
    bf16* Vt      = (bf16*)p;                p += (long)H * HD * S * 2;
    bf16* emb_bf  = (bf16*)p;                p += (long)V * D * 2;
    bf16* qkvW_bf = (bf16*)p;                p += (long)NLAYERS * 3 * D * D * 2;
    bf16* outW_bf = (bf16*)p;                p += (long)NLAYERS * D * D * 2;
    bf16* fc1W_bf = (bf16*)p;                p += (long)NLAYERS * 2 * DFF * D * 2;
    bf16* fc2W_bf = (bf16*)p;                p += (long)NLAYERS * D * DFF * 2;

    // ---- weight prep (LoRA fold, direct A reads) ----
    k_fold<<<dim3(D / 256, 3 * D / 8, NLAYERS), 256, 0, stream>>>(qkv_W, qkv_A, qkv_B, qkvW_bf, 3 * D, D);
    k_fold<<<dim3(D / 256, D / 8, NLAYERS), 256, 0, stream>>>(out_W, out_A, out_B, outW_bf, D, D);
    k_fold<<<dim3(D / 256, 2 * DFF / 8, NLAYERS), 256, 0, stream>>>(fc1_W, fc1_A, fc1_B, fc1W_bf, 2 * DFF, D);
    k_fold<<<dim3(DFF / 256, D / 8, NLAYERS), 256, 0, stream>>>(fc2_W, fc2_A, fc2_B, fc2W_bf, D, DFF);
    {
        long n = (long)V * D;
        k_cvt<<<(n / 4 + 255) / 256, 256, 0, stream>>>(emb, emb_bf, n);
    }

    k_embed<<<S, 256, 0, stream>>>(ids, emb, x);

    const int NWG_QKV = (3 * D / 128) * 16;   // 288
    const int NWG_FC1 = (DFF / 128) * 16;     // 384
    const int NWG_SM  = (S / 64) * (D / 128); // 192
    const int NWG_LMH = (16000 / 128) * 16;   // 2000 per half

    for (int l = 0; l < NLAYERS; l++) {
        // ---- attention block ----
        k_ln_bf<<<S, 256, 0, stream>>>(x, ln1_g + l * D, ln1_b + l * D, h_bf);
        k_gemm_qkv<<<NWG_QKV, 256, 0, stream>>>(h_bf, qkvW_bf + (long)l * 3 * D * D, Qh, Kh, Vt, NWG_QKV);
        k_attn_mfma<<<dim3(S / 64, H), 256, 0, stream>>>(Qh, Kh, Vt, slopes, ao_bf);
        k_gemm_small<1><<<NWG_SM, 256, 0, stream>>>(ao_bf, outW_bf + (long)l * D * D, x, D, D, ls1 + l * D, NWG_SM);

        // ---- FFN block ----
        k_ln_bf<<<S, 256, 0, stream>>>(x, ln2_g + l * D, ln2_b + l * D, h_bf);
        k_gemm_fc1<<<NWG_FC1, 256, 0, stream>>>(h_bf, fc1W_bf + (long)l * 2 * DFF * D, hid_bf, NWG_FC1);
        k_gemm_small<2><<<NWG_SM, 256, 0, stream>>>(hid_bf, fc2W_bf + (long)l * D * DFF, x, D, DFF, ls2 + l * D, NWG_SM);
    }

    // ---- final LN + tied lm_head (split into two N halves) ----
    k_ln_bf<<<S, 256, 0, stream>>>(x, lnf_g, lnf_b, h_bf);
    k_gemm_bf<false, 0><<<NWG_LMH, 256, 0, stream>>>(h_bf, emb_bf, (float*)d_out, V, D, nullptr, NWG_LMH, 0);
    k_gemm_bf<false, 1><<<NWG_LMH, 256, 0, stream>>>(h_bf, emb_bf + (long)16000 * D, (float*)d_out, V, D, nullptr, NWG_LMH, 16000);
}

// Round 7
// 1276.795 us; speedup vs baseline: 8.5068x; 1.0358x over previous
//
#include <hip/hip_runtime.h>
#include <hip/hip_bf16.h>
#include <stdint.h>

#define S 2048
#define D 768
#define H 12
#define HD 64
#define V 32000
#define R 32
#define DFF 3072
#define NLAYERS 4
#define EPS 1e-6f

typedef __bf16 bf16;
typedef __bf16 bf16x4 __attribute__((ext_vector_type(4)));
typedef __bf16 bf16x8 __attribute__((ext_vector_type(8)));
typedef float f32x4 __attribute__((ext_vector_type(4)));

// 1D grid, XCD-bijective swizzle (nwg % 8 == 0 for all grids), M-fastest so
// consecutive logical blocks share one B-panel (L2 reuse).
__device__ __forceinline__ int swz_logical(int nwg) {
    int id = blockIdx.x;
    int q = nwg >> 3;
    return (id & 7) * q + (id >> 3);
}

// ---------------- fp32 -> bf16 conversion ----------------
__global__ __launch_bounds__(256) void k_cvt(const float* __restrict__ in,
                                             bf16* __restrict__ out, long n) {
    long i = ((long)blockIdx.x * 256 + threadIdx.x) * 4;
    if (i >= n) return;
    float4 v = *(const float4*)(in + i);
    bf16x4 o;
    o.x = (bf16)v.x; o.y = (bf16)v.y; o.z = (bf16)v.z; o.w = (bf16)v.w;
    *(bf16x4*)(out + i) = o;
}

// ---- LoRA fold (A staged in LDS): Wb[n,k] = bf16(W[n,k] + (1/R)*sum_r A[k,r]*B[r,n])
__global__ __launch_bounds__(256) void k_fold(const float* __restrict__ W,
                                              const float* __restrict__ A,
                                              const float* __restrict__ B,
                                              bf16* __restrict__ Wb,
                                              int N, int K) {
    __shared__ float As[256][33];   // [k_local][r], +1 pad
    int l = blockIdx.z;
    const float* Wl = W + (long)l * N * K;
    const float* Al = A + (long)l * K * R;
    const float* Bl = B + (long)l * R * N;
    bf16* Wbl = Wb + (long)l * N * K;
    int t = threadIdx.x;
    long k0 = (long)blockIdx.x * 256;
    int n0 = blockIdx.y * 8;
    const float* Ab = Al + k0 * R;
    #pragma unroll
    for (int i = 0; i < 32; ++i) {
        int idx = i * 256 + t;
        As[idx >> 5][idx & 31] = Ab[idx];
    }
    __syncthreads();
    long k = k0 + t;
    float acc[8];
    #pragma unroll
    for (int j = 0; j < 8; ++j) acc[j] = Wl[(long)(n0 + j) * K + k];
    for (int r = 0; r < R; ++r) {
        float a = As[t][r] * (1.0f / R);
        #pragma unroll
        for (int j = 0; j < 8; ++j)
            acc[j] = fmaf(a, Bl[(long)r * N + n0 + j], acc[j]);
    }
    #pragma unroll
    for (int j = 0; j < 8; ++j) Wbl[(long)(n0 + j) * K + k] = (bf16)acc[j];
}

// ---------------- embedding gather ----------------
__global__ void k_embed(const int* __restrict__ ids, const float* __restrict__ emb,
                        float* __restrict__ x) {
    int s = blockIdx.x;
    int row = ids[s];
    for (int d = threadIdx.x; d < D; d += blockDim.x)
        x[s * D + d] = emb[row * D + d];
}

// ---------------- layernorm -> bf16 out ----------------
__global__ __launch_bounds__(256) void k_ln_bf(const float* __restrict__ x,
                                               const float* __restrict__ g,
                                               const float* __restrict__ b,
                                               bf16* __restrict__ out) {
    int s = blockIdx.x;
    int t = threadIdx.x;
    const float* xr = x + s * D;
    float e0 = xr[t], e1 = xr[t + 256], e2 = xr[t + 512];
    float sum = e0 + e1 + e2;
    float sq = e0 * e0 + e1 * e1 + e2 * e2;
    #pragma unroll
    for (int m = 1; m < 64; m <<= 1) {
        sum += __shfl_xor(sum, m);
        sq  += __shfl_xor(sq, m);
    }
    __shared__ float ssum[4], ssq[4];
    int w = t >> 6;
    if ((t & 63) == 0) { ssum[w] = sum; ssq[w] = sq; }
    __syncthreads();
    sum = ssum[0] + ssum[1] + ssum[2] + ssum[3];
    sq  = ssq[0] + ssq[1] + ssq[2] + ssq[3];
    float mean = sum * (1.0f / D);
    float var  = sq * (1.0f / D) - mean * mean;
    float rs = rsqrtf(var + EPS);
    bf16* orow = out + (long)s * D;
    orow[t]       = (bf16)((e0 - mean) * rs * g[t]       + b[t]);
    orow[t + 256] = (bf16)((e1 - mean) * rs * g[t + 256] + b[t + 256]);
    orow[t + 512] = (bf16)((e2 - mean) * rs * g[t + 512] + b[t + 512]);
}

// ---------------- shared GEMM machinery ----------------
__device__ __forceinline__ void gload16(const bf16* g, bf16* l) {
    __builtin_amdgcn_global_load_lds(
        (const __attribute__((address_space(1))) void*)g,
        (__attribute__((address_space(3))) void*)l, 16, 0, 0);
}

// 128x128 tile: C[M,N(stride)] = X[M,K] @ W[N,K]^T ; col offset ncol0 for
// split-N dispatch. RESID: C += ls[col]*acc in place.
template <bool RESID, int TAG>
__global__ __launch_bounds__(256) void k_gemm_bf(const bf16* __restrict__ X,
                                                 const bf16* __restrict__ W,
                                                 float* __restrict__ C,
                                                 int N, int K,
                                                 const float* __restrict__ ls,
                                                 int nwg, int ncol0) {
    __shared__ bf16 At[128 * 32];
    __shared__ bf16 Bt[128 * 32];
    int tid = threadIdx.x;
    int w = tid >> 6, lane = tid & 63;
    int logical = swz_logical(nwg);
    long m0 = (long)(logical & 15) * 128;
    long n0 = (long)(logical >> 4) * 128;
    int wr = (w >> 1) * 64, wc = (w & 1) * 64;
    int c0 = w, c1 = w + 4;
    int rA0 = c0 * 16 + (lane >> 2);
    int rA1 = c1 * 16 + (lane >> 2);
    int ck = (lane & 3) * 8;
    int fr = lane & 15;
    int fo = (lane >> 4) * 8;
    f32x4 acc[4][4] = {};
    for (int k0 = 0; k0 < K; k0 += 32) {
        gload16(X + (m0 + rA0) * K + k0 + ck, At + c0 * 512);
        gload16(X + (m0 + rA1) * K + k0 + ck, At + c1 * 512);
        gload16(W + (n0 + rA0) * K + k0 + ck, Bt + c0 * 512);
        gload16(W + (n0 + rA1) * K + k0 + ck, Bt + c1 * 512);
        __syncthreads();
        bf16x8 a[4], b[4];
        #pragma unroll
        for (int m = 0; m < 4; m++)
            a[m] = *(const bf16x8*)(At + (wr + m * 16 + fr) * 32 + fo);
        #pragma unroll
        for (int n = 0; n < 4; n++)
            b[n] = *(const bf16x8*)(Bt + (wc + n * 16 + fr) * 32 + fo);
        #pragma unroll
        for (int m = 0; m < 4; m++)
            #pragma unroll
            for (int n = 0; n < 4; n++)
                acc[m][n] = __builtin_amdgcn_mfma_f32_16x16x32_bf16(a[m], b[n], acc[m][n], 0, 0, 0);
        __syncthreads();
    }
    int cr = (lane >> 4) * 4, cc = lane & 15;
    #pragma unroll
    for (int m = 0; m < 4; m++)
        #pragma unroll
        for (int n = 0; n < 4; n++) {
            long col = ncol0 + n0 + wc + n * 16 + cc;
            #pragma unroll
            for (int r = 0; r < 4; r++) {
                long idx = (m0 + wr + m * 16 + cr + r) * N + col;
                if (RESID)
                    C[idx] = fmaf(ls[col], acc[m][n][r], C[idx]);
                else
                    C[idx] = acc[m][n][r];
            }
        }
}

// 64x128 tile for small-N GEMMs (out-proj, fc2). Always RESID.
template <int TAG>
__global__ __launch_bounds__(256) void k_gemm_small(const bf16* __restrict__ X,
                                                    const bf16* __restrict__ W,
                                                    float* __restrict__ C,
                                                    int N, int K,
                                                    const float* __restrict__ ls,
                                                    int nwg) {
    __shared__ bf16 At[64 * 32];
    __shared__ bf16 Bt[128 * 32];
    int tid = threadIdx.x;
    int w = tid >> 6, lane = tid & 63;
    int logical = swz_logical(nwg);
    long m0 = (long)(logical & 31) * 64;
    long n0 = (long)(logical >> 5) * 128;
    int wr = (w >> 1) * 32, wc = (w & 1) * 64;
    int rA = tid >> 2;
    int rB0 = tid >> 2, rB1 = 64 + (tid >> 2);
    int ck = (tid & 3) * 8;
    int fr = lane & 15;
    int fo = (lane >> 4) * 8;
    f32x4 acc[2][4] = {};
    for (int k0 = 0; k0 < K; k0 += 32) {
        gload16(X + (m0 + rA) * K + k0 + ck, At + tid * 8);
        gload16(W + (n0 + rB0) * K + k0 + ck, Bt + tid * 8);
        gload16(W + (n0 + rB1) * K + k0 + ck, Bt + 2048 + tid * 8);
        __syncthreads();
        bf16x8 a[2], b[4];
        #pragma unroll
        for (int m = 0; m < 2; m++)
            a[m] = *(const bf16x8*)(At + (wr + m * 16 + fr) * 32 + fo);
        #pragma unroll
        for (int n = 0; n < 4; n++)
            b[n] = *(const bf16x8*)(Bt + (wc + n * 16 + fr) * 32 + fo);
        #pragma unroll
        for (int m = 0; m < 2; m++)
            #pragma unroll
            for (int n = 0; n < 4; n++)
                acc[m][n] = __builtin_amdgcn_mfma_f32_16x16x32_bf16(a[m], b[n], acc[m][n], 0, 0, 0);
        __syncthreads();
    }
    int cr = (lane >> 4) * 4, cc = lane & 15;
    #pragma unroll
    for (int m = 0; m < 2; m++)
        #pragma unroll
        for (int n = 0; n < 4; n++) {
            long col = n0 + wc + n * 16 + cc;
            #pragma unroll
            for (int r = 0; r < 4; r++) {
                long idx = (m0 + wr + m * 16 + cr + r) * N + col;
                C[idx] = fmaf(ls[col], acc[m][n][r], C[idx]);
            }
        }
}

// qkv GEMM with fused split: cols [0,768)->Qh (x0.125), [768,1536)->Kh,
// [1536,2304)->Vt transposed ([col][s]).
__global__ __launch_bounds__(256) void k_gemm_qkv(const bf16* __restrict__ X,
                                                  const bf16* __restrict__ W,
                                                  bf16* __restrict__ Qh,
                                                  bf16* __restrict__ Kh,
                                                  bf16* __restrict__ Vt,
                                                  int nwg) {
    const int K = D;
    __shared__ bf16 At[128 * 32];
    __shared__ bf16 Bt[128 * 32];
    int tid = threadIdx.x;
    int w = tid >> 6, lane = tid & 63;
    int logical = swz_logical(nwg);
    long m0 = (long)(logical & 15) * 128;
    long n0 = (long)(logical >> 4) * 128;
    int wr = (w >> 1) * 64, wc = (w & 1) * 64;
    int c0 = w, c1 = w + 4;
    int rA0 = c0 * 16 + (lane >> 2);
    int rA1 = c1 * 16 + (lane >> 2);
    int ck = (lane & 3) * 8;
    int fr = lane & 15;
    int fo = (lane >> 4) * 8;
    f32x4 acc[4][4] = {};
    for (int k0 = 0; k0 < K; k0 += 32) {
        gload16(X + (m0 + rA0) * K + k0 + ck, At + c0 * 512);
        gload16(X + (m0 + rA1) * K + k0 + ck, At + c1 * 512);
        gload16(W + (n0 + rA0) * K + k0 + ck, Bt + c0 * 512);
        gload16(W + (n0 + rA1) * K + k0 + ck, Bt + c1 * 512);
        __syncthreads();
        bf16x8 a[4], b[4];
        #pragma unroll
        for (int m = 0; m < 4; m++)
            a[m] = *(const bf16x8*)(At + (wr + m * 16 + fr) * 32 + fo);
        #pragma unroll
        for (int n = 0; n < 4; n++)
            b[n] = *(const bf16x8*)(Bt + (wc + n * 16 + fr) * 32 + fo);
        #pragma unroll
        for (int m = 0; m < 4; m++)
            #pragma unroll
            for (int n = 0; n < 4; n++)
                acc[m][n] = __builtin_amdgcn_mfma_f32_16x16x32_bf16(a[m], b[n], acc[m][n], 0, 0, 0);
        __syncthreads();
    }
    int cr = (lane >> 4) * 4, cc = lane & 15;
    if (n0 < 1536) {
        bf16* dst = (n0 < 768) ? Qh : Kh;
        float scale = (n0 < 768) ? 0.125f : 1.0f;
        int base = (n0 < 768) ? (int)n0 : (int)n0 - 768;
        #pragma unroll
        for (int m = 0; m < 4; m++)
            #pragma unroll
            for (int n = 0; n < 4; n++) {
                int col = base + wc + n * 16 + cc;
                int h = col >> 6, d = col & 63;
                #pragma unroll
                for (int r = 0; r < 4; r++) {
                    long s = m0 + wr + m * 16 + cr + r;
                    dst[((long)h * S + s) * HD + d] = (bf16)(acc[m][n][r] * scale);
                }
            }
    } else {
        int base = (int)n0 - 1536;
        #pragma unroll
        for (int m = 0; m < 4; m++)
            #pragma unroll
            for (int n = 0; n < 4; n++) {
                int col = base + wc + n * 16 + cc;
                long s0 = m0 + wr + m * 16 + cr;
                bf16x4 ob;
                #pragma unroll
                for (int r = 0; r < 4; r++) ob[r] = (bf16)acc[m][n][r];
                *(bf16x4*)(Vt + (long)col * S + s0) = ob;
            }
    }
}

// fc1 GEMM with fused SwiGLU.
__global__ __launch_bounds__(256) void k_gemm_fc1(const bf16* __restrict__ X,
                                                  const bf16* __restrict__ W,
                                                  bf16* __restrict__ hb,
                                                  int nwg) {
    const int K = D;
    __shared__ bf16 At[128 * 32];
    __shared__ bf16 Bg[128 * 32];
    __shared__ bf16 Ba[128 * 32];
    int tid = threadIdx.x;
    int w = tid >> 6, lane = tid & 63;
    int logical = swz_logical(nwg);
    long m0 = (long)(logical & 15) * 128;
    long f0 = (long)(logical >> 4) * 128;
    int wr = (w >> 1) * 64, wc = (w & 1) * 64;
    int c0 = w, c1 = w + 4;
    int rA0 = c0 * 16 + (lane >> 2);
    int rA1 = c1 * 16 + (lane >> 2);
    int ck = (lane & 3) * 8;
    int fr = lane & 15;
    int fo = (lane >> 4) * 8;
    const bf16* Wg = W + f0 * K;
    const bf16* Wa = W + ((long)DFF + f0) * K;
    f32x4 accG[4][4] = {}, accA[4][4] = {};
    for (int k0 = 0; k0 < K; k0 += 32) {
        gload16(X + (m0 + rA0) * K + k0 + ck, At + c0 * 512);
        gload16(X + (m0 + rA1) * K + k0 + ck, At + c1 * 512);
        gload16(Wg + (long)rA0 * K + k0 + ck, Bg + c0 * 512);
        gload16(Wg + (long)rA1 * K + k0 + ck, Bg + c1 * 512);
        gload16(Wa + (long)rA0 * K + k0 + ck, Ba + c0 * 512);
        gload16(Wa + (long)rA1 * K + k0 + ck, Ba + c1 * 512);
        __syncthreads();
        bf16x8 a[4], bg[4], ba[4];
        #pragma unroll
        for (int m = 0; m < 4; m++)
            a[m] = *(const bf16x8*)(At + (wr + m * 16 + fr) * 32 + fo);
        #pragma unroll
        for (int n = 0; n < 4; n++) {
            bg[n] = *(const bf16x8*)(Bg + (wc + n * 16 + fr) * 32 + fo);
            ba[n] = *(const bf16x8*)(Ba + (wc + n * 16 + fr) * 32 + fo);
        }
        #pragma unroll
        for (int m = 0; m < 4; m++)
            #pragma unroll
            for (int n = 0; n < 4; n++) {
                accG[m][n] = __builtin_amdgcn_mfma_f32_16x16x32_bf16(a[m], bg[n], accG[m][n], 0, 0, 0);
                accA[m][n] = __builtin_amdgcn_mfma_f32_16x16x32_bf16(a[m], ba[n], accA[m][n], 0, 0, 0);
            }
        __syncthreads();
    }
    int cr = (lane >> 4) * 4, cc = lane & 15;
    #pragma unroll
    for (int m = 0; m < 4; m++)
        #pragma unroll
        for (int n = 0; n < 4; n++) {
            long col = f0 + wc + n * 16 + cc;
            #pragma unroll
            for (int r = 0; r < 4; r++) {
                long s = m0 + wr + m * 16 + cr + r;
                float gv = accG[m][n][r], av = accA[m][n][r];
                float sig = 1.0f / (1.0f + __expf(-gv));
                hb[s * DFF + col] = (bf16)(gv * sig * av);
            }
        }
}

// ---------------- flash attention, MFMA, ALiBi+causal ----------------
// 4 waves x 16 q-rows (QBLK=64), KVBLK=128: one stage + 2 barriers per 128 j.
// K/V swizzle: store source-chunk XOR, read same XOR (involution, rule 21).
__global__ __launch_bounds__(256) void k_attn_mfma(const bf16* __restrict__ Qh,
                                                   const bf16* __restrict__ Kh,
                                                   const bf16* __restrict__ Vt,
                                                   const float* __restrict__ slopes,
                                                   bf16* __restrict__ ao) {
    __shared__ bf16 Kl[128 * 64];        // [j][d], 8 chunks/row, XOR(r&7)
    __shared__ bf16 Vl[64 * 128];        // [d][j], 16 chunks/row, XOR(rd&7)
    __shared__ bf16 Pl[4][16 * 136];     // per-wave P[q][j], +8 pad
    int tid = threadIdx.x;
    int w = tid >> 6, lane = tid & 63;
    int fr = lane & 15, g = lane >> 4;
    int qb = gridDim.x - 1 - blockIdx.x;   // longest blocks launch first
    int q0 = qb * 64;
    int h = blockIdx.y;
    int ntiles = qb / 2 + 1;               // 128-wide j tiles
    float slope = slopes[h];

    const bf16* qrow = Qh + ((long)h * S + q0 + w * 16 + fr) * HD;
    bf16x8 qf0 = *(const bf16x8*)(qrow + g * 8);
    bf16x8 qf1 = *(const bf16x8*)(qrow + 32 + g * 8);

    const bf16* Kg = Kh + (long)h * S * HD;
    const bf16* Vg = Vt + (long)h * HD * S;

    float m = -1e9f, l = 0.f;
    f32x4 o[4] = {};
    int qg = q0 + w * 16 + fr;

    for (int t = 0; t < ntiles; ++t) {
        int j0 = t * 128;
        __syncthreads();   // previous tile's LDS reads done
        #pragma unroll
        for (int i = 0; i < 4; ++i) {      // K: 1024 chunks of 16B
            int ci = tid + 256 * i;
            int r = ci >> 3, c = (ci & 7) ^ (r & 7);
            gload16(Kg + (long)(j0 + r) * HD + c * 8, Kl + ci * 8);
        }
        #pragma unroll
        for (int i = 0; i < 4; ++i) {      // V: 1024 chunks of 16B
            int ci = tid + 256 * i;
            int rd = ci >> 4, cj = (ci & 15) ^ (rd & 7);
            gload16(Vg + (long)rd * S + j0 + cj * 8, Vl + ci * 8);
        }
        __syncthreads();   // compiler drains vmcnt before barrier

        // ---- QK^T: C[j][q], 8 j-subtiles of 16 ----
        f32x4 sc[8];
        __builtin_amdgcn_s_setprio(1);
        #pragma unroll
        for (int jt = 0; jt < 8; ++jt) {
            int jr = jt * 16 + fr;
            bf16x8 kf0 = *(const bf16x8*)(Kl + jr * 64 + ((g ^ (jr & 7)) * 8));
            bf16x8 kf1 = *(const bf16x8*)(Kl + jr * 64 + (((g + 4) ^ (jr & 7)) * 8));
            f32x4 z = {};
            z = __builtin_amdgcn_mfma_f32_16x16x32_bf16(kf0, qf0, z, 0, 0, 0);
            z = __builtin_amdgcn_mfma_f32_16x16x32_bf16(kf1, qf1, z, 0, 0, 0);
            sc[jt] = z;
        }
        __builtin_amdgcn_s_setprio(0);

        // ---- mask + ALiBi + online softmax (lane owns q = qg) ----
        bool need_mask = (j0 + 127) > (q0 + w * 16);   // wave-uniform
        float mt = -1e9f;
        if (need_mask) {
            #pragma unroll
            for (int jt = 0; jt < 8; ++jt)
                #pragma unroll
                for (int r = 0; r < 4; ++r) {
                    int rel = (j0 + jt * 16 + g * 4 + r) - qg;
                    float v = (rel <= 0) ? fmaf(slope, (float)rel, sc[jt][r]) : -1e9f;
                    sc[jt][r] = v;
                    mt = fmaxf(mt, v);
                }
        } else {
            #pragma unroll
            for (int jt = 0; jt < 8; ++jt)
                #pragma unroll
                for (int r = 0; r < 4; ++r) {
                    int rel = (j0 + jt * 16 + g * 4 + r) - qg;
                    float v = fmaf(slope, (float)rel, sc[jt][r]);
                    sc[jt][r] = v;
                    mt = fmaxf(mt, v);
                }
        }
        mt = fmaxf(mt, __shfl_xor(mt, 16));
        mt = fmaxf(mt, __shfl_xor(mt, 32));
        float mnew = fmaxf(m, mt);
        float factor = __expf(m - mnew);
        float psum = 0.f;
        #pragma unroll
        for (int jt = 0; jt < 8; ++jt) {
            bf16x4 pb;
            #pragma unroll
            for (int r = 0; r < 4; ++r) {
                float p = __expf(sc[jt][r] - mnew);
                psum += p;
                pb[r] = (bf16)p;
            }
            *(bf16x4*)(&Pl[w][fr * 136 + jt * 16 + g * 4]) = pb;
        }
        psum += __shfl_xor(psum, 16);
        psum += __shfl_xor(psum, 32);
        l = l * factor + psum;
        m = mnew;
        #pragma unroll
        for (int dt = 0; dt < 4; ++dt)
            #pragma unroll
            for (int r = 0; r < 4; ++r) o[dt][r] *= factor;

        // ---- PV: C[d][q], K=128 in 4 k-slices ----
        bf16x8 pf[4];
        #pragma unroll
        for (int ks = 0; ks < 4; ++ks)
            pf[ks] = *(const bf16x8*)(&Pl[w][fr * 136 + ks * 32 + g * 8]);
        __builtin_amdgcn_s_setprio(1);
        #pragma unroll
        for (int dt = 0; dt < 4; ++dt) {
            int dr = dt * 16 + fr;
            #pragma unroll
            for (int ks = 0; ks < 4; ++ks) {
                bf16x8 vf = *(const bf16x8*)(Vl + dr * 128 + (((ks * 4 + g) ^ (dr & 7)) * 8));
                o[dt] = __builtin_amdgcn_mfma_f32_16x16x32_bf16(vf, pf[ks], o[dt], 0, 0, 0);
            }
        }
        __builtin_amdgcn_s_setprio(0);
    }
    float inv = 1.0f / l;
    bf16* orow = ao + ((long)(q0 + w * 16 + fr)) * D + h * HD;
    #pragma unroll
    for (int dt = 0; dt < 4; ++dt) {
        bf16x4 ob;
        #pragma unroll
        for (int r = 0; r < 4; ++r) ob[r] = (bf16)(o[dt][r] * inv);
        *(bf16x4*)(orow + dt * 16 + g * 4) = ob;
    }
}

extern "C" void kernel_launch(void* const* d_in, const int* in_sizes, int n_in,
                              void* d_out, int out_size, void* d_ws, size_t ws_size,
                              hipStream_t stream) {
    const int*   ids    = (const int*)d_in[0];
    const float* emb    = (const float*)d_in[1];
    const float* slopes = (const float*)d_in[2];
    const float* ln1_g  = (const float*)d_in[3];
    const float* ln1_b  = (const float*)d_in[4];
    const float* qkv_W  = (const float*)d_in[5];
    const float* qkv_A  = (const float*)d_in[6];
    const float* qkv_B  = (const float*)d_in[7];
    const float* out_W  = (const float*)d_in[8];
    const float* out_A  = (const float*)d_in[9];
    const float* out_B  = (const float*)d_in[10];
    const float* ln2_g  = (const float*)d_in[11];
    const float* ln2_b  = (const float*)d_in[12];
    const float* fc1_W  = (const float*)d_in[13];
    const float* fc1_A  = (const float*)d_in[14];
    const float* fc1_B  = (const float*)d_in[15];
    const float* fc2_W  = (const float*)d_in[16];
    const float* fc2_A  = (const float*)d_in[17];
    const float* fc2_B  = (const float*)d_in[18];
    const float* ls1    = (const float*)d_in[19];
    const float* ls2    = (const float*)d_in[20];
    const float* lnf_g  = (const float*)d_in[21];
    const float* lnf_b  = (const float*)d_in[22];

    // ---- workspace layout ----
    char* p = (char*)d_ws;
    float* x      = (float*)p;               p += (long)S * D * 4;
    bf16* h_bf    = (bf16*)p;                p += (long)S * D * 2;
    bf16* ao_bf   = (bf16*)p;                p += (long)S * D * 2;
    bf16* hid_bf  = (bf16*)p;                p += (long)S * DFF * 2;
    bf16* Qh      = (bf16*)p;                p += (long)H * S * HD * 2;
    bf16* Kh      = (bf16*)p;                p += (long)H * S * HD * 2;
    bf16* Vt      = (bf16*)p;                p += (long)H * HD * S * 2;
    bf16* emb_bf  = (bf16*)p;                p += (long)V * D * 2;
    bf16* qkvW_bf = (bf16*)p;                p += (long)NLAYERS * 3 * D * D * 2;
    bf16* outW_bf = (bf16*)p;                p += (long)NLAYERS * D * D * 2;
    bf16* fc1W_bf = (bf16*)p;                p += (long)NLAYERS * 2 * DFF * D * 2;
    bf16* fc2W_bf = (bf16*)p;                p += (long)NLAYERS * D * DFF * 2;

    // ---- weight prep (LoRA fold) ----
    k_fold<<<dim3(D / 256, 3 * D / 8, NLAYERS), 256, 0, stream>>>(qkv_W, qkv_A, qkv_B, qkvW_bf, 3 * D, D);
    k_fold<<<dim3(D / 256, D / 8, NLAYERS), 256, 0, stream>>>(out_W, out_A, out_B, outW_bf, D, D);
    k_fold<<<dim3(D / 256, 2 * DFF / 8, NLAYERS), 256, 0, stream>>>(fc1_W, fc1_A, fc1_B, fc1W_bf, 2 * DFF, D);
    k_fold<<<dim3(DFF / 256, D / 8, NLAYERS), 256, 0, stream>>>(fc2_W, fc2_A, fc2_B, fc2W_bf, D, DFF);
    {
        long n = (long)V * D;
        k_cvt<<<(n / 4 + 255) / 256, 256, 0, stream>>>(emb, emb_bf, n);
    }

    k_embed<<<S, 256, 0, stream>>>(ids, emb, x);

    const int NWG_QKV = (3 * D / 128) * 16;   // 288
    const int NWG_FC1 = (DFF / 128) * 16;     // 384
    const int NWG_SM  = (S / 64) * (D / 128); // 192
    const int NWG_LMH = (16000 / 128) * 16;   // 2000 per half

    for (int l = 0; l < NLAYERS; l++) {
        // ---- attention block ----
        k_ln_bf<<<S, 256, 0, stream>>>(x, ln1_g + l * D, ln1_b + l * D, h_bf);
        k_gemm_qkv<<<NWG_QKV, 256, 0, stream>>>(h_bf, qkvW_bf + (long)l * 3 * D * D, Qh, Kh, Vt, NWG_QKV);
        k_attn_mfma<<<dim3(S / 64, H), 256, 0, stream>>>(Qh, Kh, Vt, slopes, ao_bf);
        k_gemm_small<1><<<NWG_SM, 256, 0, stream>>>(ao_bf, outW_bf + (long)l * D * D, x, D, D, ls1 + l * D, NWG_SM);

        // ---- FFN block ----
        k_ln_bf<<<S, 256, 0, stream>>>(x, ln2_g + l * D, ln2_b + l * D, h_bf);
        k_gemm_fc1<<<NWG_FC1, 256, 0, stream>>>(h_bf, fc1W_bf + (long)l * 2 * DFF * D, hid_bf, NWG_FC1);
        k_gemm_small<2><<<NWG_SM, 256, 0, stream>>>(hid_bf, fc2W_bf + (long)l * D * DFF, x, D, DFF, ls2 + l * D, NWG_SM);
    }

    // ---- final LN + tied lm_head (split into two N halves) ----
    k_ln_bf<<<S, 256, 0, stream>>>(x, lnf_g, lnf_b, h_bf);
    k_gemm_bf<false, 0><<<NWG_LMH, 256, 0, stream>>>(h_bf, emb_bf, (float*)d_out, V, D, nullptr, NWG_LMH, 0);
    k_gemm_bf<false, 1><<<NWG_LMH, 256, 0, stream>>>(h_bf, emb_bf + (long)16000 * D, (float*)d_out, V, D, nullptr, NWG_LMH, 16000);
}